// Round 18
// baseline (608.048 us; speedup 1.0000x reference)
//
#include <hip/hip_runtime.h>

typedef unsigned short u16;
typedef unsigned int u32;
typedef __attribute__((ext_vector_type(8))) short bf16x8;
typedef __attribute__((ext_vector_type(4))) float f32x4;
typedef __attribute__((ext_vector_type(4))) int i32x4;

#define DEV __device__ __forceinline__

DEV u16 f2bf(float f){
  unsigned u = __float_as_uint(f);
  u += 0x7fffu + ((u >> 16) & 1u);
  return (u16)(u >> 16);
}
DEV float bf2f(u16 h){ return __uint_as_float(((unsigned)h) << 16); }

// Inverse spiral map: pixel index (0..80) -> spiral token position (0..80).
DEV int spiral_t(int pix){
  int px = pix / 9, py = pix % 9;
  int dr = px - 4, dc = py - 4;
  int ar = dr < 0 ? -dr : dr, ac = dc < 0 ? -dc : dc;
  int r = ar > ac ? ar : ac;
  if (r == 0) return 0;
  int start = 1 + 4*r*(r-1);
  if (dr == -r && dc >= -r+1) return start + dc + r - 1;
  if (dc == r)  return start + 2*r + dr + r - 1;
  if (dr == r)  return start + 4*r + dc + r;
  return start + 6*r + dr + r;
}

// ---------------- conv3d (1->8, k=3^3, SAME) + BN + ReLU -> h1 bf16 [B][81][240]
// v3: thread owns a (pix,co) column; 27 weights in VGPRs; dd-sliding 3-slice
// register window; 30 outputs -> 15 dword stores.
// MERGED: blocks >= 4096 run the k_wt transform (Wt2 prep).
__global__ __launch_bounds__(256) void k_conv3d(const float* __restrict__ x,
    const float* __restrict__ w3, const float* __restrict__ b3,
    const float* __restrict__ g3, const float* __restrict__ be3,
    const float* __restrict__ m3, const float* __restrict__ v3,
    const float* __restrict__ w2c, const float* __restrict__ g2,
    const float* __restrict__ v2,
    u16* __restrict__ h1, u16* __restrict__ Wt2){
  __shared__ float tile[3993];   // 33 slices x 121 ([dd+1][px+1][py+1], zero-padded)
  __shared__ float wle[216];
  __shared__ float sc[8], sh[8];
  int b = blockIdx.x, tid = threadIdx.x;

  if (b >= 4096){                // ---- wt blocks ----
    int idx = (b - 4096)*256 + tid;
    int kk = idx & 31;
    int o  = (idx >> 5) & 63;
    int tile2 = idx >> 11;        // 0..71
    int dxy = tile2 >> 3;
    int chunk = tile2 & 7;
    int ch = chunk*32 + kk;
    float v = 0.f;
    if (ch < 240){
      float s2 = g2[o] * rsqrtf(v2[o] + 1e-5f);
      v = w2c[(o*240 + ch)*9 + dxy] * s2;
    }
    Wt2[idx] = f2bf(v);
    return;
  }

  for (int i = tid; i < 3993; i += 256) tile[i] = 0.f;
  if (tid < 216) wle[tid] = w3[tid];
  if (tid < 8){
    float s = g3[tid]*rsqrtf(v3[tid]+1e-5f);
    sc[tid] = s;
    sh[tid] = (b3[tid]-m3[tid])*s + be3[tid];
  }
  __syncthreads();
  const float* xin = x + b*2430;
  for (int i = tid; i < 2430; i += 256){
    int dd = i / 81, rem = i % 81;
    int px = rem / 9, py = rem % 9;
    tile[(dd+1)*121 + (px+1)*11 + (py+1)] = xin[i];
  }
  __syncthreads();
  u16* hb = h1 + (size_t)b*19440;

  for (int col = tid; col < 648; col += 256){
    int pix = col >> 3, co = col & 7;
    int px = pix / 9, py = pix % 9;
    const float* base = tile + px*11 + py;     // slice s at base + s*121
    float wp[27];
    #pragma unroll
    for (int q=0;q<27;q++) wp[q] = wle[co*27+q];
    float scv = sc[co], shv = sh[co];

    float s0[9], s1[9], s2[9];
#define LSL(S, SL)                                                            \
    { const float* tp2 = base + (SL)*121;                                     \
      _Pragma("unroll")                                                       \
      for (int kx=0;kx<3;kx++)                                                \
        _Pragma("unroll")                                                     \
        for (int ky=0;ky<3;ky++) S[kx*3+ky] = tp2[kx*11+ky]; }
#define DOT3(A, SA, SB, SC)                                                   \
    { A = 0.f;                                                                \
      _Pragma("unroll")                                                       \
      for (int q=0;q<9;q++) A = fmaf(SA[q], wp[q], A);                        \
      _Pragma("unroll")                                                       \
      for (int q=0;q<9;q++) A = fmaf(SB[q], wp[9+q], A);                      \
      _Pragma("unroll")                                                       \
      for (int q=0;q<9;q++) A = fmaf(SC[q], wp[18+q], A); }

    LSL(s0, 0); LSL(s1, 1); LSL(s2, 2);
    u16 outv[30];
    #pragma unroll
    for (int d3 = 0; d3 < 30; d3 += 3){
      float a;
      DOT3(a, s0, s1, s2);
      outv[d3] = f2bf(fmaxf(fmaf(a, scv, shv), 0.f));
      LSL(s0, d3+3);
      DOT3(a, s1, s2, s0);
      outv[d3+1] = f2bf(fmaxf(fmaf(a, scv, shv), 0.f));
      LSL(s1, d3+4);
      DOT3(a, s2, s0, s1);
      outv[d3+2] = f2bf(fmaxf(fmaf(a, scv, shv), 0.f));
      LSL(s2, d3+5);                 // max slice index 32 -> in-bounds (33 slices)
    }
#undef LSL
#undef DOT3
    u32* dst = (u32*)(hb + pix*240 + co*30);
    #pragma unroll
    for (int q=0;q<15;q++) dst[q] = ((u32)outv[2*q+1] << 16) | (u32)outv[2*q];
  }
}

// ---------------- conv2d MFMA GEMM + BN + ReLU + pos_emb + FUSED LN1/tsum/SToken
// v10 @ launch_bounds(256,1): 2-way K-split. Wave (p=wv>>1, q=wv&1): pair p owns
// rows [96p,96p+96), wave q owns K-chunks {2q,2q+1} -> per-wave B reads halve.
// Round-12's spill was the (256,2) bound capping VGPR at 128; at ~240 VGPR the
// HW still runs 2 waves/SIMD (512-reg file), so (256,1) keeps occupancy.
__global__ __launch_bounds__(256, 1) void k_conv2d(const u16* __restrict__ h1,
    const u16* __restrict__ Wt2,
    const float* __restrict__ b2c, const float* __restrict__ g2,
    const float* __restrict__ be2, const float* __restrict__ m2,
    const float* __restrict__ v2,
    const float* __restrict__ pos_emb, const float* __restrict__ cls_tok,
    const float* __restrict__ ln1_g, const float* __restrict__ ln1_b,
    const float* __restrict__ Wst, const float* __restrict__ bst,
    const float* __restrict__ bias_st,
    u16* __restrict__ xn, float* __restrict__ tsum, float* __restrict__ sqs){
  // rows r in [0,162) at r*496 (480B data + 16B zero-ch-pad); zrow (496B zeros) at 80352
  __shared__ __align__(16) char smem[80848];
  const int ZROW = 80352;
  int tid = threadIdx.x;
  int wv = tid >> 6, ln = tid & 63;
  int lq = ln >> 4, lr = ln & 15;
  int p = wv >> 1, q = wv & 1;        // pair, K-half
  int img0 = blockIdx.x*2;
  size_t grow0 = (size_t)img0*81;

  int bln = lr*32 + lq*8;    // u16 offset of this lane's B-frag within a [64o][32k] tile
  int c0 = q*2, c1 = q*2 + 1;

#define LOADB(TAP, C, B)                                                        \
    { const u16* Bt_ = Wt2 + (TAP)*16384 + bln;                                 \
      _Pragma("unroll")                                                         \
      for (int kk=0;kk<2;kk++)                                                  \
        _Pragma("unroll")                                                       \
        for (int j=0;j<4;j++)                                                   \
          B[kk][j] = *(const bf16x8*)(Bt_ + ((C)*2+kk)*2048 + j*512); }

  // B prologue (this wave's two chunks of tap 0) BEFORE the barrier.
  bf16x8 bA[2][4], bB[2][4];
  LOADB(0, c0, bA);
  LOADB(0, c1, bB);

  // zero fills: per-row ch-pad [480,496) + zrow
  for (int r = tid; r < 162; r += 256)
    *(i32x4*)(smem + r*496 + 480) = (i32x4){0,0,0,0};
  if (tid < 31) *(i32x4*)(smem + ZROW + tid*16) = (i32x4){0,0,0,0};
  // stage 2 images: 77,760B contiguous from h1, coalesced
  {
    const u16* src = h1 + grow0*240;
    for (int idx = tid; idx < 162*30; idx += 256){
      int r = idx / 30, c = idx % 30;
      *(i32x4*)(smem + r*496 + c*16) = *(const i32x4*)(src + idx*8);
    }
  }
  __syncthreads();

  f32x4 acc[6][4];
  #pragma unroll
  for (int i=0;i<6;i++)
    #pragma unroll
    for (int j=0;j<4;j++) acc[i][j] = (f32x4){0.f,0.f,0.f,0.f};

  int aC0[6], aC1[6];
  bf16x8 afr[6][2];

#define CALCADDR(TAP)                                                           \
  { int dx = (TAP)/3 - 1, dy = (TAP)%3 - 1;                                     \
    _Pragma("unroll")                                                           \
    for (int rt=0;rt<6;rt++){                                                   \
      int row = p*96 + rt*16 + lr;                                              \
      int pix = row % 81;                                                       \
      int px = pix/9, py = pix%9;                                               \
      int px2 = px + dx, py2 = py + dy;                                         \
      bool valid = (row < 162) && ((unsigned)px2 < 9u) && ((unsigned)py2 < 9u); \
      int nrow = (row - pix) + px2*9 + py2;                                     \
      int base = valid ? nrow*496 : ZROW;                                       \
      aC0[rt] = base + lq*16;                                                   \
      aC1[rt] = base + 64 + lq*16;                                              \
    } }

  // load A-frags for one rt, chunk C (C==3 upper half spills past the 16B pad -> zeros)
#define LOADA1(RT, C)                                                           \
    { afr[RT][0] = *(const bf16x8*)(smem + aC0[RT] + (C)*128);                  \
      int a1a_ = ((C)==3) ? ((lq==3) ? ZROW : aC1[RT] + 384)                    \
                          : (aC1[RT] + (C)*128);                                \
      afr[RT][1] = *(const bf16x8*)(smem + a1a_); }

  // one chunk-group: 8 MFMA per rt with buffer B, then refill afr[rt] for chunk NC
#define GROUP(B, NC)                                                            \
    { _Pragma("unroll")                                                         \
      for (int rt=0;rt<6;rt++){                                                 \
        __builtin_amdgcn_s_setprio(1);                                          \
        _Pragma("unroll")                                                       \
        for (int j=0;j<4;j++)                                                   \
          acc[rt][j] = __builtin_amdgcn_mfma_f32_16x16x32_bf16(afr[rt][0], B[0][j], acc[rt][j], 0, 0, 0); \
        _Pragma("unroll")                                                       \
        for (int j=0;j<4;j++)                                                   \
          acc[rt][j] = __builtin_amdgcn_mfma_f32_16x16x32_bf16(afr[rt][1], B[1][j], acc[rt][j], 0, 0, 0); \
        __builtin_amdgcn_s_setprio(0);                                          \
        LOADA1(rt, NC);                                                         \
      } }

  // prologue: addresses + A-frags for (tap0, c0)
  CALCADDR(0);
  #pragma unroll
  for (int rt=0;rt<6;rt++){ LOADA1(rt, c0); }

  for (int tap = 0; tap < 9; tap++){
    int ntap = (tap < 8) ? tap + 1 : 8;      // clamp: tail reload, unused
    // group A: chunk c0 of tap; refills load (tap, c1) with current addrs
    GROUP(bA, c1);
    LOADB(ntap, c0, bA);                     // distance-2 refill
    CALCADDR(ntap);                          // next-tap addrs (VALU overlaps)
    // group B: chunk c1 of tap; refills load (ntap, c0) with new addrs
    GROUP(bB, c0);
    LOADB(ntap, c1, bB);
  }
#undef CALCADDR
#undef LOADB
#undef LOADA1
#undef GROUP

  // ---- cross-wave K-reduction through (now dead) image LDS ----
  __syncthreads();                           // all image reads done
  float* ex = (float*)smem;                  // [2 pair][96 row][64 col] f32 = 49152B
  int rtw0 = q ? 0 : 3;                      // write partner's rts
  #pragma unroll
  for (int k=0;k<3;k++){
    int rt = rtw0 + k;
    #pragma unroll
    for (int e=0;e<4;e++)
      #pragma unroll
      for (int j=0;j<4;j++)
        ex[p*6144 + (rt*16 + lq*4 + e)*64 + j*16 + lr] = acc[rt][j][e];
  }
  __syncthreads();
  int rtr0 = q ? 3 : 0;                      // my epilogue rts
  #pragma unroll
  for (int k=0;k<3;k++){
    int rt = rtr0 + k;
    #pragma unroll
    for (int e=0;e<4;e++)
      #pragma unroll
      for (int j=0;j<4;j++)
        acc[rt][j][e] += ex[p*6144 + (rt*16 + lq*4 + e)*64 + j*16 + lr];
  }
  __syncthreads();                           // ex reads done; smem reusable again

  // per-lane epilogue constants
  float t2c[4], lg[4], lb[4];
  #pragma unroll
  for (int j=0;j<4;j++){
    int col = j*16 + lr;
    float s2 = g2[col]*rsqrtf(v2[col]+1e-5f);
    t2c[j] = (b2c[col]-m2[col])*s2 + be2[col];
    lg[j] = ln1_g[col]; lb[j] = ln1_b[col];
  }

  float st0[4]={0,0,0,0}, st1[4]={0,0,0,0};   // per-image tok sums (4 d per lane)
  float sx0[4]={0,0,0,0}, sx1[4]={0,0,0,0};   // per-image xn sums

  #pragma unroll
  for (int k=0;k<3;k++){
    int rt = rtr0 + k;
    #pragma unroll
    for (int e=0;e<4;e++){
      int row = p*96 + rt*16 + lq*4 + e;       // same row across the 16-lane lr group
      if (row < 162){
        int im = (row >= 81);
        int pix = row - im*81;
        int tsp = spiral_t(pix);
        const float* pe = pos_emb + (1+tsp)*64;
        float y[4], m1 = 0.f, m2v = 0.f;
        #pragma unroll
        for (int j=0;j<4;j++){
          y[j] = fmaxf(acc[rt][j][e] + t2c[j], 0.f) + pe[j*16+lr];
          m1 += y[j]; m2v = fmaf(y[j], y[j], m2v);
        }
        #pragma unroll
        for (int off=1; off<16; off<<=1){
          m1  += __shfl_xor(m1,  off, 64);
          m2v += __shfl_xor(m2v, off, 64);
        }
        float mean = m1*(1.f/64.f);
        float var  = m2v*(1.f/64.f) - mean*mean;
        float rs = rsqrtf(var + 1e-5f);
        u16* dst = xn + ((size_t)(img0+im)*82 + 1 + tsp)*64;
        #pragma unroll
        for (int j=0;j<4;j++){
          float xnv = (y[j]-mean)*rs*lg[j] + lb[j];
          dst[j*16+lr] = f2bf(xnv);
          if (im == 0){ st0[j] += y[j]; sx0[j] += xnv; }
          else        { st1[j] += y[j]; sx1[j] += xnv; }
        }
      }
    }
  }

  // reduce over lq (lanes ln^16, ln^32 hold same d = j*16+lr)
  #pragma unroll
  for (int j=0;j<4;j++){
    st0[j] += __shfl_xor(st0[j],16,64); st0[j] += __shfl_xor(st0[j],32,64);
    st1[j] += __shfl_xor(st1[j],16,64); st1[j] += __shfl_xor(st1[j],32,64);
    sx0[j] += __shfl_xor(sx0[j],16,64); sx0[j] += __shfl_xor(sx0[j],32,64);
    sx1[j] += __shfl_xor(sx1[j],16,64); sx1[j] += __shfl_xor(sx1[j],32,64);
  }
  float* partT = (float*)smem;            // [4 wv][2 img][64 d] = 2KB
  float* partX = (float*)(smem + 2048);   // [4 wv][2 img][64 d]
  float* xsumL = (float*)(smem + 4096);   // [2 img][64 d]
  if (lq == 0){
    #pragma unroll
    for (int j=0;j<4;j++){
      partT[wv*128 +       j*16+lr] = st0[j];
      partT[wv*128 + 64  + j*16+lr] = st1[j];
      partX[wv*128 +       j*16+lr] = sx0[j];
      partX[wv*128 + 64  + j*16+lr] = sx1[j];
    }
  }
  __syncthreads();
  if (tid < 128){
    int im = tid >> 6, d = tid & 63;
    float tt = partT[im*64+d] + partT[128+im*64+d] + partT[256+im*64+d] + partT[384+im*64+d];
    float xx = partX[im*64+d] + partX[128+im*64+d] + partX[256+im*64+d] + partX[384+im*64+d];
    // cls token (batch-constant): LN over d within this wave
    float clsv = cls_tok[d] + pos_emb[d];
    float c1v = clsv, c2v = clsv*clsv;
    #pragma unroll
    for (int off=1; off<64; off<<=1){ c1v += __shfl_xor(c1v, off, 64); c2v += __shfl_xor(c2v, off, 64); }
    float cm = c1v*(1.f/64.f), cv = c2v*(1.f/64.f) - cm*cm;
    float cxn = (clsv - cm)*rsqrtf(cv + 1e-5f)*ln1_g[d] + ln1_b[d];
    xn[((size_t)(img0+im)*82)*64 + d] = f2bf(cxn);
    tsum[(size_t)(img0+im)*64 + d] = tt + clsv;
    xsumL[im*64 + d] = (xx + cxn) * (1.f/82.f);
  }
  __syncthreads();
  {
    // squeeze matvec, split-k over 2 threads per (im,d): tid = im*128 + d*2 + half
    int im = tid >> 7, d2 = tid & 127;
    int d = d2 >> 1, half = d2 & 1;
    float a = 0.f;
    int k0 = half*32;
    #pragma unroll
    for (int k=0;k<32;k++) a = fmaf(xsumL[im*64 + k0+k], Wst[(k0+k)*64+d], a);
    a += __shfl_xor(a, 1, 64);
    if (half == 0){
      a += bst[d];
      a = fmaxf(a, 0.f);
      a = 1.f/(1.f + __expf(-a));
      sqs[(size_t)(img0+im)*64 + d] = a + bias_st[d];
    }
  }
}

// ---------------- FUSED B/C/delta GEMM + S6 prep + scan + pool + LN2 + MLP (block = batch)
__global__ __launch_bounds__(256, 2) void k_fuse(const u16* __restrict__ xn,
    const float* __restrict__ tsum, const float* __restrict__ sqs,
    const float* __restrict__ Wb, const float* __restrict__ Wc, const float* __restrict__ Wd,
    const float* __restrict__ bbv, const float* __restrict__ bcv, const float* __restrict__ bdv,
    const float* __restrict__ delta_p, const float* __restrict__ A_p,
    const float* __restrict__ ln2_g, const float* __restrict__ ln2_b,
    const float* __restrict__ Wm1, const float* __restrict__ bm1,
    const float* __restrict__ Wm2, const float* __restrict__ bm2,
    float* __restrict__ out){
  __shared__ __align__(16) char xnL[96*128];   // swizzled rows: byte ^ ((row&7)<<4)
  __shared__ u16 AxL[96][66], BxL[96][66], CxL[96][66];
  int tid = threadIdx.x;
  int wv = tid >> 6, ln = tid & 63;
  int lq = ln >> 4, lr = ln & 15;
  int b = blockIdx.x;

  // B-frags first (L2-hot): cc = wv*16+lr for each of Wb/Wc/Wd
  bf16x8 bfr[3][2];
  {
    int cc = wv*16 + lr;
    const float* Ws[3] = {Wb, Wc, Wd};
    #pragma unroll
    for (int w=0;w<3;w++)
      #pragma unroll
      for (int kk=0;kk<2;kk++){
        int k0 = kk*32 + lq*8;
        bf16x8 f;
        #pragma unroll
        for (int e=0;e<8;e++) f[e] = (short)f2bf(Ws[w][(k0+e)*64 + cc]);
        bfr[w][kk] = f;
      }
  }

  // stage xn[b] rows 0..81 (swizzled), zero rows 82..95
  {
    const u16* src = xn + (size_t)b*82*64;
    for (int idx = tid; idx < 656; idx += 256){       // 82 rows x 8 x 16B
      int r = idx >> 3, c = idx & 7;
      *(i32x4*)(xnL + r*128 + ((c*16) ^ ((r&7)<<4))) = *(const i32x4*)(src + idx*8);
    }
    for (int idx = tid; idx < 112; idx += 256){       // rows 82..95
      int r = 82 + (idx >> 3), c = idx & 7;
      *(i32x4*)(xnL + r*128 + ((c*16) ^ ((r&7)<<4))) = (i32x4){0,0,0,0};
    }
  }
  __syncthreads();

  f32x4 acc[6][3];
  #pragma unroll
  for (int i=0;i<6;i++)
    #pragma unroll
    for (int w=0;w<3;w++) acc[i][w] = (f32x4){0.f,0.f,0.f,0.f};

  #pragma unroll
  for (int rt=0;rt<6;rt++){
    int row = rt*16 + lr;
    bf16x8 afr[2];
    #pragma unroll
    for (int kk=0;kk<2;kk++)
      afr[kk] = *(const bf16x8*)(xnL + row*128 + ((kk*64 + lq*16) ^ ((row&7)<<4)));
    #pragma unroll
    for (int kk=0;kk<2;kk++)
      #pragma unroll
      for (int w=0;w<3;w++)
        acc[rt][w] = __builtin_amdgcn_mfma_f32_16x16x32_bf16(afr[kk], bfr[w][kk], acc[rt][w], 0, 0, 0);
  }

  // epilogue: lane holds (B0, C, Draw) for d = wv*16+lr at token t
  {
    int d = wv*16 + lr;
    float bB = bbv[d], bC = bcv[d], bD = bdv[d];
    #pragma unroll
    for (int rt=0;rt<6;rt++){
      #pragma unroll
      for (int e=0;e<4;e++){
        int t = rt*16 + lq*4 + e;
        if (t < 82){
          float B0 = acc[rt][0][e] + bB;
          float Cv = acc[rt][1][e] + bC;
          float Dr = acc[rt][2][e] + bD + delta_p[t*64+d];
          float D  = 1.f/(1.f + __expf(-Dr));
          float xv = bf2f(*(const u16*)(xnL + t*128 + ((d*2) ^ ((t&7)<<4))));
          AxL[t][d] = f2bf(D * A_p[t*64+d]);
          BxL[t][d] = f2bf(D * B0 * xv);
          CxL[t][d] = f2bf(Cv);
        }
      }
    }
  }
  __syncthreads();

  if (wv == 0){
    int d = ln;
    float sq = sqs[(size_t)b*64 + d];
    float s = 0.f, racc = 0.f;
    for (int t = 0; t < 82; t++){
      float a  = bf2f(AxL[t][d]);
      float bx = bf2f(BxL[t][d]);
      float c  = bf2f(CxL[t][d]);
      float xv = bf2f(*(const u16*)(xnL + t*128 + ((d*2) ^ ((t&7)<<4))));
      s = fmaf(a, s, bx);
      float o = fmaf(c, s, sq*xv);
      float z = 1.f/(1.f + __expf(-xv));
      racc = fmaf(o, z, racc);
    }
    float pooled = (tsum[(size_t)b*64 + d] + racc) * (1.f/82.f);
    float s1 = pooled, s2v = pooled*pooled;
    #pragma unroll
    for (int off=32; off>0; off>>=1){ s1 += __shfl_xor(s1, off, 64); s2v += __shfl_xor(s2v, off, 64); }
    float mean = s1*(1.f/64.f), var = s2v*(1.f/64.f) - mean*mean;
    float yn = (pooled - mean)*rsqrtf(var + 1e-5f)*ln2_g[d] + ln2_b[d];
    float a1 = bm1[d];
    for (int k=0;k<64;k++) a1 = fmaf(__shfl(yn, k, 64), Wm1[k*64+d], a1);
    float hg = 0.5f*a1*(1.f + erff(a1*0.70710678118654752f));
    float a2 = bm2[d];
    for (int k=0;k<64;k++) a2 = fmaf(__shfl(hg, k, 64), Wm2[k*64+d], a2);
    out[(size_t)b*64 + d] = pooled + a2;
  }
}

extern "C" void kernel_launch(void* const* d_in, const int* in_sizes, int n_in,
                              void* d_out, int out_size, void* d_ws, size_t ws_size,
                              hipStream_t stream){
  const float* x       = (const float*)d_in[0];
  const float* w3      = (const float*)d_in[1];
  const float* b3      = (const float*)d_in[2];
  const float* g3      = (const float*)d_in[3];
  const float* be3     = (const float*)d_in[4];
  const float* m3      = (const float*)d_in[5];
  const float* v3      = (const float*)d_in[6];
  const float* w2c     = (const float*)d_in[7];
  const float* b2c     = (const float*)d_in[8];
  const float* g2      = (const float*)d_in[9];
  const float* be2     = (const float*)d_in[10];
  const float* m2      = (const float*)d_in[11];
  const float* v2      = (const float*)d_in[12];
  const float* pos_emb = (const float*)d_in[13];
  const float* cls_tok = (const float*)d_in[14];
  const float* ln1_g   = (const float*)d_in[15];
  const float* ln1_b   = (const float*)d_in[16];
  const float* Wb      = (const float*)d_in[17];
  const float* bbv     = (const float*)d_in[18];
  const float* Wc      = (const float*)d_in[19];
  const float* bc      = (const float*)d_in[20];
  const float* Wd      = (const float*)d_in[21];
  const float* bd      = (const float*)d_in[22];
  const float* delta_p = (const float*)d_in[23];
  const float* A_p     = (const float*)d_in[24];
  const float* Wst     = (const float*)d_in[25];
  const float* bst     = (const float*)d_in[26];
  const float* bias_st = (const float*)d_in[27];
  const float* ln2_g   = (const float*)d_in[28];
  const float* ln2_b   = (const float*)d_in[29];
  const float* Wm1     = (const float*)d_in[30];
  const float* bm1     = (const float*)d_in[31];
  const float* Wm2     = (const float*)d_in[32];
  const float* bm2     = (const float*)d_in[33];

  // workspace layout (bytes), peak = 204,660,736:
  //   h1   [0,          159252480)  (conv3d -> conv2d)
  //   Wt2  [159252480,  159547392)  (conv3d wt-blocks -> conv2d)
  //   xn   [159571968,  202563584)  bf16 [4096][82][64]  (conv2d -> k_fuse)
  //   tsum [202563584,  203612160)  f32  [4096][64]      (conv2d -> k_fuse)
  //   sqs  [203612160,  204660736)  f32  [4096][64]      (conv2d -> k_fuse)
  char* ws = (char*)d_ws;
  u16*   h1   = (u16*)ws;
  u16*   Wt2  = (u16*)(ws + 159252480);
  u16*   xnb  = (u16*)(ws + 159571968);
  float* tsum = (float*)(ws + 202563584);
  float* sqs  = (float*)(ws + 203612160);

  k_conv3d<<<4672, 256, 0, stream>>>(x, w3, b3, g3, be3, m3, v3,
                                     w2c, g2, v2, h1, Wt2);
  k_conv2d<<<2048, 256, 0, stream>>>(h1, Wt2, b2c, g2, be2, m2, v2,
                                     pos_emb, cls_tok, ln1_g, ln1_b,
                                     Wst, bst, bias_st, xnb, tsum, sqs);
  k_fuse  <<<4096, 256, 0, stream>>>(xnb, tsum, sqs, Wb, Wc, Wd, bbv, bc, bd,
                                     delta_p, A_p, ln2_g, ln2_b,
                                     Wm1, bm1, Wm2, bm2, (float*)d_out);
}

// Round 19
// 362.258 us; speedup vs baseline: 1.6785x; 1.6785x over previous
//
#include <hip/hip_runtime.h>

typedef unsigned short u16;
typedef unsigned int u32;
typedef __attribute__((ext_vector_type(8))) short bf16x8;
typedef __attribute__((ext_vector_type(4))) float f32x4;
typedef __attribute__((ext_vector_type(4))) int i32x4;

#define DEV __device__ __forceinline__

DEV u16 f2bf(float f){
  unsigned u = __float_as_uint(f);
  u += 0x7fffu + ((u >> 16) & 1u);
  return (u16)(u >> 16);
}
DEV float bf2f(u16 h){ return __uint_as_float(((unsigned)h) << 16); }

// Inverse spiral map: pixel index (0..80) -> spiral token position (0..80).
DEV int spiral_t(int pix){
  int px = pix / 9, py = pix % 9;
  int dr = px - 4, dc = py - 4;
  int ar = dr < 0 ? -dr : dr, ac = dc < 0 ? -dc : dc;
  int r = ar > ac ? ar : ac;
  if (r == 0) return 0;
  int start = 1 + 4*r*(r-1);
  if (dr == -r && dc >= -r+1) return start + dc + r - 1;
  if (dc == r)  return start + 2*r + dr + r - 1;
  if (dr == r)  return start + 4*r + dc + r;
  return start + 6*r + dr + r;
}

// ---------------- conv3d (1->8, k=3^3, SAME) + BN + ReLU -> h1 bf16 [B][81][240]
// v4: 2-column ILP pairing. Thread processes cols (tid, tid+256) simultaneously
// (same co -> shared weights); interleaved DOT3 chains hide LDS latency that v3's
// serial chain exposed (~50 cyc/DOT3). Tail cols 512+tid run pair with A==B.
// MERGED: blocks >= 4096 run the k_wt transform (Wt2 prep).
__global__ __launch_bounds__(256) void k_conv3d(const float* __restrict__ x,
    const float* __restrict__ w3, const float* __restrict__ b3,
    const float* __restrict__ g3, const float* __restrict__ be3,
    const float* __restrict__ m3, const float* __restrict__ v3,
    const float* __restrict__ w2c, const float* __restrict__ g2,
    const float* __restrict__ v2,
    u16* __restrict__ h1, u16* __restrict__ Wt2){
  __shared__ float tile[3993];   // 33 slices x 121 ([dd+1][px+1][py+1], zero-padded)
  __shared__ float wle[216];
  __shared__ float sc[8], sh[8];
  int b = blockIdx.x, tid = threadIdx.x;

  if (b >= 4096){                // ---- wt blocks ----
    int idx = (b - 4096)*256 + tid;
    int kk = idx & 31;
    int o  = (idx >> 5) & 63;
    int tile2 = idx >> 11;        // 0..71
    int dxy = tile2 >> 3;
    int chunk = tile2 & 7;
    int ch = chunk*32 + kk;
    float v = 0.f;
    if (ch < 240){
      float s2 = g2[o] * rsqrtf(v2[o] + 1e-5f);
      v = w2c[(o*240 + ch)*9 + dxy] * s2;
    }
    Wt2[idx] = f2bf(v);
    return;
  }

  for (int i = tid; i < 3993; i += 256) tile[i] = 0.f;
  if (tid < 216) wle[tid] = w3[tid];
  if (tid < 8){
    float s = g3[tid]*rsqrtf(v3[tid]+1e-5f);
    sc[tid] = s;
    sh[tid] = (b3[tid]-m3[tid])*s + be3[tid];
  }
  __syncthreads();
  const float* xin = x + b*2430;
  for (int i = tid; i < 2430; i += 256){
    int dd = i / 81, rem = i % 81;
    int px = rem / 9, py = rem % 9;
    tile[(dd+1)*121 + (px+1)*11 + (py+1)] = xin[i];
  }
  __syncthreads();
  u16* hb = h1 + (size_t)b*19440;

#define LSL(S, BASE, SL)                                                      \
    { const float* tp2 = (BASE) + (SL)*121;                                   \
      _Pragma("unroll")                                                       \
      for (int kx=0;kx<3;kx++)                                                \
        _Pragma("unroll")                                                     \
        for (int ky=0;ky<3;ky++) S[kx*3+ky] = tp2[kx*11+ky]; }
#define DOT3(A, SA, SB, SC)                                                   \
    { A = 0.f;                                                                \
      _Pragma("unroll")                                                       \
      for (int q=0;q<9;q++) A = fmaf(SA[q], wp[q], A);                        \
      _Pragma("unroll")                                                       \
      for (int q=0;q<9;q++) A = fmaf(SB[q], wp[9+q], A);                      \
      _Pragma("unroll")                                                       \
      for (int q=0;q<9;q++) A = fmaf(SC[q], wp[18+q], A); }

#define CONVPAIR(COLA, COLB, STOREB)                                          \
  { int pixA = (COLA) >> 3, coA = (COLA) & 7;                                 \
    int pixB = (COLB) >> 3;                                                   \
    const float* baseA = tile + (pixA/9)*11 + (pixA%9);                       \
    const float* baseB = tile + (pixB/9)*11 + (pixB%9);                       \
    float wp[27];                                                             \
    _Pragma("unroll")                                                         \
    for (int q=0;q<27;q++) wp[q] = wle[coA*27+q];                             \
    float scv = sc[coA], shv = sh[coA];                                       \
    float sA0[9],sA1[9],sA2[9],sB0[9],sB1[9],sB2[9];                          \
    LSL(sA0, baseA, 0); LSL(sB0, baseB, 0);                                   \
    LSL(sA1, baseA, 1); LSL(sB1, baseB, 1);                                   \
    LSL(sA2, baseA, 2); LSL(sB2, baseB, 2);                                   \
    u16 outA[30], outB[30];                                                   \
    _Pragma("unroll")                                                         \
    for (int d3 = 0; d3 < 30; d3 += 3){                                       \
      float aA, aB;                                                           \
      DOT3(aA, sA0, sA1, sA2); DOT3(aB, sB0, sB1, sB2);                       \
      outA[d3] = f2bf(fmaxf(fmaf(aA, scv, shv), 0.f));                        \
      outB[d3] = f2bf(fmaxf(fmaf(aB, scv, shv), 0.f));                        \
      LSL(sA0, baseA, d3+3); LSL(sB0, baseB, d3+3);                           \
      DOT3(aA, sA1, sA2, sA0); DOT3(aB, sB1, sB2, sB0);                       \
      outA[d3+1] = f2bf(fmaxf(fmaf(aA, scv, shv), 0.f));                      \
      outB[d3+1] = f2bf(fmaxf(fmaf(aB, scv, shv), 0.f));                      \
      LSL(sA1, baseA, d3+4); LSL(sB1, baseB, d3+4);                           \
      DOT3(aA, sA2, sA0, sA1); DOT3(aB, sB2, sB0, sB1);                       \
      outA[d3+2] = f2bf(fmaxf(fmaf(aA, scv, shv), 0.f));                      \
      outB[d3+2] = f2bf(fmaxf(fmaf(aB, scv, shv), 0.f));                      \
      LSL(sA2, baseA, d3+5); LSL(sB2, baseB, d3+5);                           \
    }                                                                         \
    u32* dstA = (u32*)(hb + pixA*240 + coA*30);                               \
    _Pragma("unroll")                                                         \
    for (int q2=0;q2<15;q2++) dstA[q2] = ((u32)outA[2*q2+1] << 16) | (u32)outA[2*q2]; \
    if (STOREB){                                                              \
      u32* dstB = (u32*)(hb + pixB*240 + coA*30);                             \
      _Pragma("unroll")                                                       \
      for (int q2=0;q2<15;q2++) dstB[q2] = ((u32)outB[2*q2+1] << 16) | (u32)outB[2*q2]; \
    } }

  CONVPAIR(tid, tid + 256, true);
  if (tid < 136){ CONVPAIR(512 + tid, 512 + tid, false); }
#undef CONVPAIR
#undef LSL
#undef DOT3
}

// ---------------- conv2d MFMA GEMM + BN + ReLU + pos_emb + FUSED LN1/tsum/SToken
// v9 (round-11/14/17): depth-2 B pipeline (3-buffer rotation), setprio around
// MFMA clusters, split-k squeeze.
__global__ __launch_bounds__(256, 2) void k_conv2d(const u16* __restrict__ h1,
    const u16* __restrict__ Wt2,
    const float* __restrict__ b2c, const float* __restrict__ g2,
    const float* __restrict__ be2, const float* __restrict__ m2,
    const float* __restrict__ v2,
    const float* __restrict__ pos_emb, const float* __restrict__ cls_tok,
    const float* __restrict__ ln1_g, const float* __restrict__ ln1_b,
    const float* __restrict__ Wst, const float* __restrict__ bst,
    const float* __restrict__ bias_st,
    u16* __restrict__ xn, float* __restrict__ tsum, float* __restrict__ sqs){
  // rows r in [0,162) at r*496 (480B data + 16B zero-ch-pad); zrow (496B zeros) at 80352
  __shared__ __align__(16) char smem[80848];
  const int ZROW = 80352;
  int tid = threadIdx.x;
  int wv = tid >> 6, ln = tid & 63;
  int lq = ln >> 4, lr = ln & 15;
  int img0 = blockIdx.x*2;
  size_t grow0 = (size_t)img0*81;

  int bln = lr*32 + lq*8;    // u16 offset of this lane's B-frag within a [64o][32k] tile

#define LOADB(TAP, C, B)                                                        \
    { const u16* Bt_ = Wt2 + (TAP)*16384 + bln;                                 \
      _Pragma("unroll")                                                         \
      for (int kk=0;kk<2;kk++)                                                  \
        _Pragma("unroll")                                                       \
        for (int j=0;j<4;j++)                                                   \
          B[kk][j] = *(const bf16x8*)(Bt_ + ((C)*2+kk)*2048 + j*512); }

  // B prologue (tap0 chunks 0,1,2) issued BEFORE the barrier
  bf16x8 bB0[2][4], bB1[2][4], bB2[2][4];
  LOADB(0, 0, bB0);
  LOADB(0, 1, bB1);
  LOADB(0, 2, bB2);

  for (int r = tid; r < 162; r += 256)
    *(i32x4*)(smem + r*496 + 480) = (i32x4){0,0,0,0};
  if (tid < 31) *(i32x4*)(smem + ZROW + tid*16) = (i32x4){0,0,0,0};
  {
    const u16* src = h1 + grow0*240;
    for (int idx = tid; idx < 162*30; idx += 256){
      int r = idx / 30, c = idx % 30;
      *(i32x4*)(smem + r*496 + c*16) = *(const i32x4*)(src + idx*8);
    }
  }
  __syncthreads();

  f32x4 acc[3][4];
  #pragma unroll
  for (int i=0;i<3;i++)
    #pragma unroll
    for (int j=0;j<4;j++) acc[i][j] = (f32x4){0.f,0.f,0.f,0.f};

#define CALCADDR(TAP, A0, A1, A13)                                              \
  { int dx = (TAP)/3 - 1, dy = (TAP)%3 - 1;                                     \
    _Pragma("unroll")                                                           \
    for (int rt=0;rt<3;rt++){                                                   \
      int row = (wv*3+rt)*16 + lr;                                              \
      int pix = row % 81;                                                       \
      int px = pix/9, py = pix%9;                                               \
      int px2 = px + dx, py2 = py + dy;                                         \
      bool valid = (row < 162) && ((unsigned)px2 < 9u) && ((unsigned)py2 < 9u); \
      int nrow = (row - pix) + px2*9 + py2;                                     \
      int base = valid ? nrow*496 : ZROW;                                       \
      A0[rt]  = base + lq*16;                                                   \
      A1[rt]  = base + 64 + lq*16;                                              \
      A13[rt] = (lq == 3) ? ZROW : (A1[rt] + 384);                              \
    } }

#define LOADA(C, SA0, SA1, SA13, A0, A1)                                        \
    { _Pragma("unroll")                                                         \
      for (int rt=0;rt<3;rt++){                                                 \
        A0[rt] = *(const bf16x8*)(smem + SA0[rt] + (C)*128);                    \
        A1[rt] = *(const bf16x8*)(smem + ((C)==3 ? SA13[rt]                     \
                                                 : SA1[rt] + (C)*128)); } }

#define DOMFMA(B, A0, A1)                                                       \
    { __builtin_amdgcn_s_setprio(1);                                            \
      _Pragma("unroll")                                                         \
      for (int rt=0;rt<3;rt++)                                                  \
        _Pragma("unroll")                                                       \
        for (int j=0;j<4;j++)                                                   \
          acc[rt][j] = __builtin_amdgcn_mfma_f32_16x16x32_bf16(A0[rt], B[0][j], acc[rt][j], 0, 0, 0); \
      _Pragma("unroll")                                                         \
      for (int rt=0;rt<3;rt++)                                                  \
        _Pragma("unroll")                                                       \
        for (int j=0;j<4;j++)                                                   \
          acc[rt][j] = __builtin_amdgcn_mfma_f32_16x16x32_bf16(A1[rt], B[1][j], acc[rt][j], 0, 0, 0); \
      __builtin_amdgcn_s_setprio(0); }

#define TAPBODY(TAPV, BA, BB, BC)                                               \
  { int ntap_ = (TAPV) < 8 ? (TAPV)+1 : 8;                                      \
    DOMFMA(BA, aAX0, aAX1);                                                     \
    LOADB((TAPV), 3, BA); LOADA(2, aC0, aC1, aC13, aAX0, aAX1);                 \
    DOMFMA(BB, aAY0, aAY1);                                                     \
    LOADB(ntap_, 0, BB); CALCADDR(ntap_, aN0, aN1, aN13);                       \
    LOADA(3, aC0, aC1, aC13, aAY0, aAY1);                                       \
    DOMFMA(BC, aAX0, aAX1);                                                     \
    LOADB(ntap_, 1, BC); LOADA(0, aN0, aN1, aN13, aAX0, aAX1);                  \
    DOMFMA(BA, aAY0, aAY1);                                                     \
    LOADB(ntap_, 2, BA); LOADA(1, aN0, aN1, aN13, aAY0, aAY1);                  \
    _Pragma("unroll")                                                           \
    for (int rt=0;rt<3;rt++){ aC0[rt]=aN0[rt]; aC1[rt]=aN1[rt]; aC13[rt]=aN13[rt]; } }

  int aC0[3], aC1[3], aC13[3];
  int aN0[3], aN1[3], aN13[3];
  bf16x8 aAX0[3], aAX1[3], aAY0[3], aAY1[3];

  CALCADDR(0, aC0, aC1, aC13);
  LOADA(0, aC0, aC1, aC13, aAX0, aAX1);
  LOADA(1, aC0, aC1, aC13, aAY0, aAY1);

  for (int t3 = 0; t3 < 9; t3 += 3){
    TAPBODY(t3+0, bB0, bB1, bB2);
    TAPBODY(t3+1, bB1, bB2, bB0);
    TAPBODY(t3+2, bB2, bB0, bB1);
  }
#undef CALCADDR
#undef LOADB
#undef LOADA
#undef DOMFMA
#undef TAPBODY

  __syncthreads();   // all image-LDS reads done; smem reusable for reductions

  float t2c[4], lg[4], lb[4];
  #pragma unroll
  for (int j=0;j<4;j++){
    int col = j*16 + lr;
    float s2 = g2[col]*rsqrtf(v2[col]+1e-5f);
    t2c[j] = (b2c[col]-m2[col])*s2 + be2[col];
    lg[j] = ln1_g[col]; lb[j] = ln1_b[col];
  }

  float st0[4]={0,0,0,0}, st1[4]={0,0,0,0};
  float sx0[4]={0,0,0,0}, sx1[4]={0,0,0,0};

  #pragma unroll
  for (int rt=0;rt<3;rt++){
    #pragma unroll
    for (int e=0;e<4;e++){
      int row = (wv*3+rt)*16 + lq*4 + e;
      if (row < 162){
        int im = (row >= 81);
        int pix = row - im*81;
        int tsp = spiral_t(pix);
        const float* pe = pos_emb + (1+tsp)*64;
        float y[4], m1 = 0.f, m2v = 0.f;
        #pragma unroll
        for (int j=0;j<4;j++){
          y[j] = fmaxf(acc[rt][j][e] + t2c[j], 0.f) + pe[j*16+lr];
          m1 += y[j]; m2v = fmaf(y[j], y[j], m2v);
        }
        #pragma unroll
        for (int off=1; off<16; off<<=1){
          m1  += __shfl_xor(m1,  off, 64);
          m2v += __shfl_xor(m2v, off, 64);
        }
        float mean = m1*(1.f/64.f);
        float var  = m2v*(1.f/64.f) - mean*mean;
        float rs = rsqrtf(var + 1e-5f);
        u16* dst = xn + ((size_t)(img0+im)*82 + 1 + tsp)*64;
        #pragma unroll
        for (int j=0;j<4;j++){
          float xnv = (y[j]-mean)*rs*lg[j] + lb[j];
          dst[j*16+lr] = f2bf(xnv);
          if (im == 0){ st0[j] += y[j]; sx0[j] += xnv; }
          else        { st1[j] += y[j]; sx1[j] += xnv; }
        }
      }
    }
  }

  #pragma unroll
  for (int j=0;j<4;j++){
    st0[j] += __shfl_xor(st0[j],16,64); st0[j] += __shfl_xor(st0[j],32,64);
    st1[j] += __shfl_xor(st1[j],16,64); st1[j] += __shfl_xor(st1[j],32,64);
    sx0[j] += __shfl_xor(sx0[j],16,64); sx0[j] += __shfl_xor(sx0[j],32,64);
    sx1[j] += __shfl_xor(sx1[j],16,64); sx1[j] += __shfl_xor(sx1[j],32,64);
  }
  float* partT = (float*)smem;            // [4 wv][2 img][64 d]
  float* partX = (float*)(smem + 2048);
  float* xsumL = (float*)(smem + 4096);
  if (lq == 0){
    #pragma unroll
    for (int j=0;j<4;j++){
      partT[wv*128 +       j*16+lr] = st0[j];
      partT[wv*128 + 64  + j*16+lr] = st1[j];
      partX[wv*128 +       j*16+lr] = sx0[j];
      partX[wv*128 + 64  + j*16+lr] = sx1[j];
    }
  }
  __syncthreads();
  if (tid < 128){
    int im = tid >> 6, d = tid & 63;
    float tt = partT[im*64+d] + partT[128+im*64+d] + partT[256+im*64+d] + partT[384+im*64+d];
    float xx = partX[im*64+d] + partX[128+im*64+d] + partX[256+im*64+d] + partX[384+im*64+d];
    float clsv = cls_tok[d] + pos_emb[d];
    float c1v = clsv, c2v = clsv*clsv;
    #pragma unroll
    for (int off=1; off<64; off<<=1){ c1v += __shfl_xor(c1v, off, 64); c2v += __shfl_xor(c2v, off, 64); }
    float cm = c1v*(1.f/64.f), cv = c2v*(1.f/64.f) - cm*cm;
    float cxn = (clsv - cm)*rsqrtf(cv + 1e-5f)*ln1_g[d] + ln1_b[d];
    xn[((size_t)(img0+im)*82)*64 + d] = f2bf(cxn);
    tsum[(size_t)(img0+im)*64 + d] = tt + clsv;
    xsumL[im*64 + d] = (xx + cxn) * (1.f/82.f);
  }
  __syncthreads();
  {
    int im = tid >> 7, d2 = tid & 127;
    int d = d2 >> 1, half = d2 & 1;
    float a = 0.f;
    int k0 = half*32;
    #pragma unroll
    for (int k=0;k<32;k++) a = fmaf(xsumL[im*64 + k0+k], Wst[(k0+k)*64+d], a);
    a += __shfl_xor(a, 1, 64);
    if (half == 0){
      a += bst[d];
      a = fmaxf(a, 0.f);
      a = 1.f/(1.f + __expf(-a));
      sqs[(size_t)(img0+im)*64 + d] = a + bias_st[d];
    }
  }
}

// ---------------- FUSED B/C/delta GEMM + S6 prep + scan + pool + LN2 + MLP (block = batch)
__global__ __launch_bounds__(256, 2) void k_fuse(const u16* __restrict__ xn,
    const float* __restrict__ tsum, const float* __restrict__ sqs,
    const float* __restrict__ Wb, const float* __restrict__ Wc, const float* __restrict__ Wd,
    const float* __restrict__ bbv, const float* __restrict__ bcv, const float* __restrict__ bdv,
    const float* __restrict__ delta_p, const float* __restrict__ A_p,
    const float* __restrict__ ln2_g, const float* __restrict__ ln2_b,
    const float* __restrict__ Wm1, const float* __restrict__ bm1,
    const float* __restrict__ Wm2, const float* __restrict__ bm2,
    float* __restrict__ out){
  __shared__ __align__(16) char xnL[96*128];   // swizzled rows: byte ^ ((row&7)<<4)
  __shared__ u16 AxL[96][66], BxL[96][66], CxL[96][66];
  int tid = threadIdx.x;
  int wv = tid >> 6, ln = tid & 63;
  int lq = ln >> 4, lr = ln & 15;
  int b = blockIdx.x;

  // B-frags first (L2-hot): cc = wv*16+lr for each of Wb/Wc/Wd
  bf16x8 bfr[3][2];
  {
    int cc = wv*16 + lr;
    const float* Ws[3] = {Wb, Wc, Wd};
    #pragma unroll
    for (int w=0;w<3;w++)
      #pragma unroll
      for (int kk=0;kk<2;kk++){
        int k0 = kk*32 + lq*8;
        bf16x8 f;
        #pragma unroll
        for (int e=0;e<8;e++) f[e] = (short)f2bf(Ws[w][(k0+e)*64 + cc]);
        bfr[w][kk] = f;
      }
  }

  // stage xn[b] rows 0..81 (swizzled), zero rows 82..95
  {
    const u16* src = xn + (size_t)b*82*64;
    for (int idx = tid; idx < 656; idx += 256){       // 82 rows x 8 x 16B
      int r = idx >> 3, c = idx & 7;
      *(i32x4*)(xnL + r*128 + ((c*16) ^ ((r&7)<<4))) = *(const i32x4*)(src + idx*8);
    }
    for (int idx = tid; idx < 112; idx += 256){       // rows 82..95
      int r = 82 + (idx >> 3), c = idx & 7;
      *(i32x4*)(xnL + r*128 + ((c*16) ^ ((r&7)<<4))) = (i32x4){0,0,0,0};
    }
  }
  __syncthreads();

  f32x4 acc[6][3];
  #pragma unroll
  for (int i=0;i<6;i++)
    #pragma unroll
    for (int w=0;w<3;w++) acc[i][w] = (f32x4){0.f,0.f,0.f,0.f};

  #pragma unroll
  for (int rt=0;rt<6;rt++){
    int row = rt*16 + lr;
    bf16x8 afr[2];
    #pragma unroll
    for (int kk=0;kk<2;kk++)
      afr[kk] = *(const bf16x8*)(xnL + row*128 + ((kk*64 + lq*16) ^ ((row&7)<<4)));
    #pragma unroll
    for (int kk=0;kk<2;kk++)
      #pragma unroll
      for (int w=0;w<3;w++)
        acc[rt][w] = __builtin_amdgcn_mfma_f32_16x16x32_bf16(afr[kk], bfr[w][kk], acc[rt][w], 0, 0, 0);
  }

  // epilogue: lane holds (B0, C, Draw) for d = wv*16+lr at token t
  {
    int d = wv*16 + lr;
    float bB = bbv[d], bC = bcv[d], bD = bdv[d];
    #pragma unroll
    for (int rt=0;rt<6;rt++){
      #pragma unroll
      for (int e=0;e<4;e++){
        int t = rt*16 + lq*4 + e;
        if (t < 82){
          float B0 = acc[rt][0][e] + bB;
          float Cv = acc[rt][1][e] + bC;
          float Dr = acc[rt][2][e] + bD + delta_p[t*64+d];
          float D  = 1.f/(1.f + __expf(-Dr));
          float xv = bf2f(*(const u16*)(xnL + t*128 + ((d*2) ^ ((t&7)<<4))));
          AxL[t][d] = f2bf(D * A_p[t*64+d]);
          BxL[t][d] = f2bf(D * B0 * xv);
          CxL[t][d] = f2bf(Cv);
        }
      }
    }
  }
  __syncthreads();

  if (wv == 0){
    int d = ln;
    float sq = sqs[(size_t)b*64 + d];
    float s = 0.f, racc = 0.f;
    for (int t = 0; t < 82; t++){
      float a  = bf2f(AxL[t][d]);
      float bx = bf2f(BxL[t][d]);
      float c  = bf2f(CxL[t][d]);
      float xv = bf2f(*(const u16*)(xnL + t*128 + ((d*2) ^ ((t&7)<<4))));
      s = fmaf(a, s, bx);
      float o = fmaf(c, s, sq*xv);
      float z = 1.f/(1.f + __expf(-xv));
      racc = fmaf(o, z, racc);
    }
    float pooled = (tsum[(size_t)b*64 + d] + racc) * (1.f/82.f);
    float s1 = pooled, s2v = pooled*pooled;
    #pragma unroll
    for (int off=32; off>0; off>>=1){ s1 += __shfl_xor(s1, off, 64); s2v += __shfl_xor(s2v, off, 64); }
    float mean = s1*(1.f/64.f), var = s2v*(1.f/64.f) - mean*mean;
    float yn = (pooled - mean)*rsqrtf(var + 1e-5f)*ln2_g[d] + ln2_b[d];
    float a1 = bm1[d];
    for (int k=0;k<64;k++) a1 = fmaf(__shfl(yn, k, 64), Wm1[k*64+d], a1);
    float hg = 0.5f*a1*(1.f + erff(a1*0.70710678118654752f));
    float a2 = bm2[d];
    for (int k=0;k<64;k++) a2 = fmaf(__shfl(hg, k, 64), Wm2[k*64+d], a2);
    out[(size_t)b*64 + d] = pooled + a2;
  }
}

extern "C" void kernel_launch(void* const* d_in, const int* in_sizes, int n_in,
                              void* d_out, int out_size, void* d_ws, size_t ws_size,
                              hipStream_t stream){
  const float* x       = (const float*)d_in[0];
  const float* w3      = (const float*)d_in[1];
  const float* b3      = (const float*)d_in[2];
  const float* g3      = (const float*)d_in[3];
  const float* be3     = (const float*)d_in[4];
  const float* m3      = (const float*)d_in[5];
  const float* v3      = (const float*)d_in[6];
  const float* w2c     = (const float*)d_in[7];
  const float* b2c     = (const float*)d_in[8];
  const float* g2      = (const float*)d_in[9];
  const float* be2     = (const float*)d_in[10];
  const float* m2      = (const float*)d_in[11];
  const float* v2      = (const float*)d_in[12];
  const float* pos_emb = (const float*)d_in[13];
  const float* cls_tok = (const float*)d_in[14];
  const float* ln1_g   = (const float*)d_in[15];
  const float* ln1_b   = (const float*)d_in[16];
  const float* Wb      = (const float*)d_in[17];
  const float* bbv     = (const float*)d_in[18];
  const float* Wc      = (const float*)d_in[19];
  const float* bc      = (const float*)d_in[20];
  const float* Wd      = (const float*)d_in[21];
  const float* bd      = (const float*)d_in[22];
  const float* delta_p = (const float*)d_in[23];
  const float* A_p     = (const float*)d_in[24];
  const float* Wst     = (const float*)d_in[25];
  const float* bst     = (const float*)d_in[26];
  const float* bias_st = (const float*)d_in[27];
  const float* ln2_g   = (const float*)d_in[28];
  const float* ln2_b   = (const float*)d_in[29];
  const float* Wm1     = (const float*)d_in[30];
  const float* bm1     = (const float*)d_in[31];
  const float* Wm2     = (const float*)d_in[32];
  const float* bm2     = (const float*)d_in[33];

  // workspace layout (bytes), peak = 204,660,736:
  //   h1   [0,          159252480)  (conv3d -> conv2d)
  //   Wt2  [159252480,  159547392)  (conv3d wt-blocks -> conv2d)
  //   xn   [159571968,  202563584)  bf16 [4096][82][64]  (conv2d -> k_fuse)
  //   tsum [202563584,  203612160)  f32  [4096][64]      (conv2d -> k_fuse)
  //   sqs  [203612160,  204660736)  f32  [4096][64]      (conv2d -> k_fuse)
  char* ws = (char*)d_ws;
  u16*   h1   = (u16*)ws;
  u16*   Wt2  = (u16*)(ws + 159252480);
  u16*   xnb  = (u16*)(ws + 159571968);
  float* tsum = (float*)(ws + 202563584);
  float* sqs  = (float*)(ws + 203612160);

  k_conv3d<<<4672, 256, 0, stream>>>(x, w3, b3, g3, be3, m3, v3,
                                     w2c, g2, v2, h1, Wt2);
  k_conv2d<<<2048, 256, 0, stream>>>(h1, Wt2, b2c, g2, be2, m2, v2,
                                     pos_emb, cls_tok, ln1_g, ln1_b,
                                     Wst, bst, bias_st, xnb, tsum, sqs);
  k_fuse  <<<4096, 256, 0, stream>>>(xnb, tsum, sqs, Wb, Wc, Wd, bbv, bc, bd,
                                     delta_p, A_p, ln2_g, ln2_b,
                                     Wm1, bm1, Wm2, bm2, (float*)d_out);
}

// Round 20
// 361.722 us; speedup vs baseline: 1.6810x; 1.0015x over previous
//
#include <hip/hip_runtime.h>

typedef unsigned short u16;
typedef unsigned int u32;
typedef __attribute__((ext_vector_type(8))) short bf16x8;
typedef __attribute__((ext_vector_type(4))) float f32x4;
typedef __attribute__((ext_vector_type(4))) int i32x4;

#define DEV __device__ __forceinline__

DEV u16 f2bf(float f){
  unsigned u = __float_as_uint(f);
  u += 0x7fffu + ((u >> 16) & 1u);
  return (u16)(u >> 16);
}
DEV float bf2f(u16 h){ return __uint_as_float(((unsigned)h) << 16); }

// Inverse spiral map: pixel index (0..80) -> spiral token position (0..80).
DEV int spiral_t(int pix){
  int px = pix / 9, py = pix % 9;
  int dr = px - 4, dc = py - 4;
  int ar = dr < 0 ? -dr : dr, ac = dc < 0 ? -dc : dc;
  int r = ar > ac ? ar : ac;
  if (r == 0) return 0;
  int start = 1 + 4*r*(r-1);
  if (dr == -r && dc >= -r+1) return start + dc + r - 1;
  if (dc == r)  return start + 2*r + dr + r - 1;
  if (dr == r)  return start + 4*r + dc + r;
  return start + 6*r + dr + r;
}

// ---------------- conv3d (1->8, k=3^3, SAME) + BN + ReLU -> h1 bf16 [B][81][240]
// v3 (round-17): thread owns a (pix,co) column; 27 weights in VGPRs; dd-sliding
// 3-slice register window; 30 outputs -> 15 dword stores.
// MERGED: blocks >= 4096 run the k_wt transform (Wt2 prep).
__global__ __launch_bounds__(256) void k_conv3d(const float* __restrict__ x,
    const float* __restrict__ w3, const float* __restrict__ b3,
    const float* __restrict__ g3, const float* __restrict__ be3,
    const float* __restrict__ m3, const float* __restrict__ v3,
    const float* __restrict__ w2c, const float* __restrict__ g2,
    const float* __restrict__ v2,
    u16* __restrict__ h1, u16* __restrict__ Wt2){
  __shared__ float tile[3993];   // 33 slices x 121 ([dd+1][px+1][py+1], zero-padded)
  __shared__ float wle[216];
  __shared__ float sc[8], sh[8];
  int b = blockIdx.x, tid = threadIdx.x;

  if (b >= 4096){                // ---- wt blocks ----
    int idx = (b - 4096)*256 + tid;
    int kk = idx & 31;
    int o  = (idx >> 5) & 63;
    int tile2 = idx >> 11;        // 0..71
    int dxy = tile2 >> 3;
    int chunk = tile2 & 7;
    int ch = chunk*32 + kk;
    float v = 0.f;
    if (ch < 240){
      float s2 = g2[o] * rsqrtf(v2[o] + 1e-5f);
      v = w2c[(o*240 + ch)*9 + dxy] * s2;
    }
    Wt2[idx] = f2bf(v);
    return;
  }

  for (int i = tid; i < 3993; i += 256) tile[i] = 0.f;
  if (tid < 216) wle[tid] = w3[tid];
  if (tid < 8){
    float s = g3[tid]*rsqrtf(v3[tid]+1e-5f);
    sc[tid] = s;
    sh[tid] = (b3[tid]-m3[tid])*s + be3[tid];
  }
  __syncthreads();
  const float* xin = x + b*2430;
  for (int i = tid; i < 2430; i += 256){
    int dd = i / 81, rem = i % 81;
    int px = rem / 9, py = rem % 9;
    tile[(dd+1)*121 + (px+1)*11 + (py+1)] = xin[i];
  }
  __syncthreads();
  u16* hb = h1 + (size_t)b*19440;

  for (int col = tid; col < 648; col += 256){
    int pix = col >> 3, co = col & 7;
    int px = pix / 9, py = pix % 9;
    const float* base = tile + px*11 + py;     // slice s at base + s*121
    float wp[27];
    #pragma unroll
    for (int q=0;q<27;q++) wp[q] = wle[co*27+q];
    float scv = sc[co], shv = sh[co];

    float s0[9], s1[9], s2[9];
#define LSL(S, SL)                                                            \
    { const float* tp2 = base + (SL)*121;                                     \
      _Pragma("unroll")                                                       \
      for (int kx=0;kx<3;kx++)                                                \
        _Pragma("unroll")                                                     \
        for (int ky=0;ky<3;ky++) S[kx*3+ky] = tp2[kx*11+ky]; }
#define DOT3(A, SA, SB, SC)                                                   \
    { A = 0.f;                                                                \
      _Pragma("unroll")                                                       \
      for (int q=0;q<9;q++) A = fmaf(SA[q], wp[q], A);                        \
      _Pragma("unroll")                                                       \
      for (int q=0;q<9;q++) A = fmaf(SB[q], wp[9+q], A);                      \
      _Pragma("unroll")                                                       \
      for (int q=0;q<9;q++) A = fmaf(SC[q], wp[18+q], A); }

    LSL(s0, 0); LSL(s1, 1); LSL(s2, 2);
    u16 outv[30];
    #pragma unroll
    for (int d3 = 0; d3 < 30; d3 += 3){
      float a;
      DOT3(a, s0, s1, s2);
      outv[d3] = f2bf(fmaxf(fmaf(a, scv, shv), 0.f));
      LSL(s0, d3+3);
      DOT3(a, s1, s2, s0);
      outv[d3+1] = f2bf(fmaxf(fmaf(a, scv, shv), 0.f));
      LSL(s1, d3+4);
      DOT3(a, s2, s0, s1);
      outv[d3+2] = f2bf(fmaxf(fmaf(a, scv, shv), 0.f));
      LSL(s2, d3+5);                 // max slice index 32 -> in-bounds (33 slices)
    }
#undef LSL
#undef DOT3
    u32* dst = (u32*)(hb + pix*240 + co*30);
    #pragma unroll
    for (int q=0;q<15;q++) dst[q] = ((u32)outv[2*q+1] << 16) | (u32)outv[2*q];
  }
}

// ---------------- conv2d MFMA GEMM + BN + ReLU + pos_emb + LN1/tsum/SToken
//                  + FUSED token mixer (B/C/delta GEMM + S6 scan + LN2 + MLP)
// v11: v9 GEMM core unchanged; epilogue writes xn to LDS (k_fuse's swizzled
// layout) instead of HBM; tsum/sqs stay in LDS; then per image the k_fuse
// logic runs in-block -> out. Removes the k_fuse kernel + 88MB HBM round-trip.
__global__ __launch_bounds__(256, 2) void k_conv2d(const u16* __restrict__ h1,
    const u16* __restrict__ Wt2,
    const float* __restrict__ b2c, const float* __restrict__ g2,
    const float* __restrict__ be2, const float* __restrict__ m2,
    const float* __restrict__ v2,
    const float* __restrict__ pos_emb, const float* __restrict__ cls_tok,
    const float* __restrict__ ln1_g, const float* __restrict__ ln1_b,
    const float* __restrict__ Wst, const float* __restrict__ bst,
    const float* __restrict__ bias_st,
    const float* __restrict__ Wb, const float* __restrict__ Wc,
    const float* __restrict__ Wd,
    const float* __restrict__ bbv, const float* __restrict__ bcv,
    const float* __restrict__ bdv,
    const float* __restrict__ delta_p, const float* __restrict__ A_p,
    const float* __restrict__ ln2_g, const float* __restrict__ ln2_b,
    const float* __restrict__ Wm1, const float* __restrict__ bm1,
    const float* __restrict__ Wm2, const float* __restrict__ bm2,
    float* __restrict__ out){
  // GEMM phase: rows r in [0,162) at r*496; zrow at 80352.
  // Fuse phase (smem reuse): xnL [2][96][128B] at 0; tsumL f32[128] at 24576;
  //   sqsL f32[128] at 25088; AxL/BxL/CxL u16[96*66] at 25600/38272/50944;
  //   partT at 63616 (2KB); partX at 65664 (2KB); xsumL at 67712 (512B).
  __shared__ __align__(16) char smem[80848];
  const int ZROW = 80352;
  const int TSUML = 24576, SQSL = 25088, AXo = 25600, BXo = 38272, CXo = 50944;
  const int PTo = 63616, PXo = 65664, XSo = 67712;
  int tid = threadIdx.x;
  int wv = tid >> 6, ln = tid & 63;
  int lq = ln >> 4, lr = ln & 15;
  int img0 = blockIdx.x*2;
  size_t grow0 = (size_t)img0*81;

  int bln = lr*32 + lq*8;    // u16 offset of this lane's B-frag within a [64o][32k] tile

#define LOADB(TAP, C, B)                                                        \
    { const u16* Bt_ = Wt2 + (TAP)*16384 + bln;                                 \
      _Pragma("unroll")                                                         \
      for (int kk=0;kk<2;kk++)                                                  \
        _Pragma("unroll")                                                       \
        for (int j=0;j<4;j++)                                                   \
          B[kk][j] = *(const bf16x8*)(Bt_ + ((C)*2+kk)*2048 + j*512); }

  // B prologue (tap0 chunks 0,1,2) issued BEFORE the barrier
  bf16x8 bB0[2][4], bB1[2][4], bB2[2][4];
  LOADB(0, 0, bB0);
  LOADB(0, 1, bB1);
  LOADB(0, 2, bB2);

  for (int r = tid; r < 162; r += 256)
    *(i32x4*)(smem + r*496 + 480) = (i32x4){0,0,0,0};
  if (tid < 31) *(i32x4*)(smem + ZROW + tid*16) = (i32x4){0,0,0,0};
  {
    const u16* src = h1 + grow0*240;
    for (int idx = tid; idx < 162*30; idx += 256){
      int r = idx / 30, c = idx % 30;
      *(i32x4*)(smem + r*496 + c*16) = *(const i32x4*)(src + idx*8);
    }
  }
  __syncthreads();

  f32x4 acc[3][4];
  #pragma unroll
  for (int i=0;i<3;i++)
    #pragma unroll
    for (int j=0;j<4;j++) acc[i][j] = (f32x4){0.f,0.f,0.f,0.f};

#define CALCADDR(TAP, A0, A1, A13)                                              \
  { int dx = (TAP)/3 - 1, dy = (TAP)%3 - 1;                                     \
    _Pragma("unroll")                                                           \
    for (int rt=0;rt<3;rt++){                                                   \
      int row = (wv*3+rt)*16 + lr;                                              \
      int pix = row % 81;                                                       \
      int px = pix/9, py = pix%9;                                               \
      int px2 = px + dx, py2 = py + dy;                                         \
      bool valid = (row < 162) && ((unsigned)px2 < 9u) && ((unsigned)py2 < 9u); \
      int nrow = (row - pix) + px2*9 + py2;                                     \
      int base = valid ? nrow*496 : ZROW;                                       \
      A0[rt]  = base + lq*16;                                                   \
      A1[rt]  = base + 64 + lq*16;                                              \
      A13[rt] = (lq == 3) ? ZROW : (A1[rt] + 384);                              \
    } }

#define LOADA(C, SA0, SA1, SA13, A0, A1)                                        \
    { _Pragma("unroll")                                                         \
      for (int rt=0;rt<3;rt++){                                                 \
        A0[rt] = *(const bf16x8*)(smem + SA0[rt] + (C)*128);                    \
        A1[rt] = *(const bf16x8*)(smem + ((C)==3 ? SA13[rt]                     \
                                                 : SA1[rt] + (C)*128)); } }

#define DOMFMA(B, A0, A1)                                                       \
    { __builtin_amdgcn_s_setprio(1);                                            \
      _Pragma("unroll")                                                         \
      for (int rt=0;rt<3;rt++)                                                  \
        _Pragma("unroll")                                                       \
        for (int j=0;j<4;j++)                                                   \
          acc[rt][j] = __builtin_amdgcn_mfma_f32_16x16x32_bf16(A0[rt], B[0][j], acc[rt][j], 0, 0, 0); \
      _Pragma("unroll")                                                         \
      for (int rt=0;rt<3;rt++)                                                  \
        _Pragma("unroll")                                                       \
        for (int j=0;j<4;j++)                                                   \
          acc[rt][j] = __builtin_amdgcn_mfma_f32_16x16x32_bf16(A1[rt], B[1][j], acc[rt][j], 0, 0, 0); \
      __builtin_amdgcn_s_setprio(0); }

#define TAPBODY(TAPV, BA, BB, BC)                                               \
  { int ntap_ = (TAPV) < 8 ? (TAPV)+1 : 8;                                      \
    DOMFMA(BA, aAX0, aAX1);                                                     \
    LOADB((TAPV), 3, BA); LOADA(2, aC0, aC1, aC13, aAX0, aAX1);                 \
    DOMFMA(BB, aAY0, aAY1);                                                     \
    LOADB(ntap_, 0, BB); CALCADDR(ntap_, aN0, aN1, aN13);                       \
    LOADA(3, aC0, aC1, aC13, aAY0, aAY1);                                       \
    DOMFMA(BC, aAX0, aAX1);                                                     \
    LOADB(ntap_, 1, BC); LOADA(0, aN0, aN1, aN13, aAX0, aAX1);                  \
    DOMFMA(BA, aAY0, aAY1);                                                     \
    LOADB(ntap_, 2, BA); LOADA(1, aN0, aN1, aN13, aAY0, aAY1);                  \
    _Pragma("unroll")                                                           \
    for (int rt=0;rt<3;rt++){ aC0[rt]=aN0[rt]; aC1[rt]=aN1[rt]; aC13[rt]=aN13[rt]; } }

  int aC0[3], aC1[3], aC13[3];
  int aN0[3], aN1[3], aN13[3];
  bf16x8 aAX0[3], aAX1[3], aAY0[3], aAY1[3];

  CALCADDR(0, aC0, aC1, aC13);
  LOADA(0, aC0, aC1, aC13, aAX0, aAX1);
  LOADA(1, aC0, aC1, aC13, aAY0, aAY1);

  for (int t3 = 0; t3 < 9; t3 += 3){
    TAPBODY(t3+0, bB0, bB1, bB2);
    TAPBODY(t3+1, bB1, bB2, bB0);
    TAPBODY(t3+2, bB2, bB0, bB1);
  }
#undef CALCADDR
#undef LOADB
#undef LOADA
#undef DOMFMA
#undef TAPBODY

  __syncthreads();   // all image-LDS reads done; smem reusable

  // zero xnL rows 82..95 for both images
  if (tid < 224){
    int im = tid / 112, r2 = tid % 112;
    int rr = 82 + (r2 >> 3), c = r2 & 7;
    *(i32x4*)(smem + im*12288 + rr*128 + ((c*16) ^ ((rr&7)<<4))) = (i32x4){0,0,0,0};
  }

  float t2c[4], lg[4], lb[4];
  #pragma unroll
  for (int j=0;j<4;j++){
    int col = j*16 + lr;
    float s2 = g2[col]*rsqrtf(v2[col]+1e-5f);
    t2c[j] = (b2c[col]-m2[col])*s2 + be2[col];
    lg[j] = ln1_g[col]; lb[j] = ln1_b[col];
  }

  float st0[4]={0,0,0,0}, st1[4]={0,0,0,0};
  float sx0[4]={0,0,0,0}, sx1[4]={0,0,0,0};

  #pragma unroll
  for (int rt=0;rt<3;rt++){
    #pragma unroll
    for (int e=0;e<4;e++){
      int row = (wv*3+rt)*16 + lq*4 + e;
      if (row < 162){
        int im = (row >= 81);
        int pix = row - im*81;
        int tsp = spiral_t(pix);
        const float* pe = pos_emb + (1+tsp)*64;
        float y[4], m1 = 0.f, m2v = 0.f;
        #pragma unroll
        for (int j=0;j<4;j++){
          y[j] = fmaxf(acc[rt][j][e] + t2c[j], 0.f) + pe[j*16+lr];
          m1 += y[j]; m2v = fmaf(y[j], y[j], m2v);
        }
        #pragma unroll
        for (int off=1; off<16; off<<=1){
          m1  += __shfl_xor(m1,  off, 64);
          m2v += __shfl_xor(m2v, off, 64);
        }
        float mean = m1*(1.f/64.f);
        float var  = m2v*(1.f/64.f) - mean*mean;
        float rs = rsqrtf(var + 1e-5f);
        int trow = 1 + tsp;
        char* dl = smem + im*12288 + trow*128;
        int sz = (trow & 7) << 4;
        #pragma unroll
        for (int j=0;j<4;j++){
          float xnv = (y[j]-mean)*rs*lg[j] + lb[j];
          *(u16*)(dl + (((j*16+lr)*2) ^ sz)) = f2bf(xnv);
          if (im == 0){ st0[j] += y[j]; sx0[j] += xnv; }
          else        { st1[j] += y[j]; sx1[j] += xnv; }
        }
      }
    }
  }

  #pragma unroll
  for (int j=0;j<4;j++){
    st0[j] += __shfl_xor(st0[j],16,64); st0[j] += __shfl_xor(st0[j],32,64);
    st1[j] += __shfl_xor(st1[j],16,64); st1[j] += __shfl_xor(st1[j],32,64);
    sx0[j] += __shfl_xor(sx0[j],16,64); sx0[j] += __shfl_xor(sx0[j],32,64);
    sx1[j] += __shfl_xor(sx1[j],16,64); sx1[j] += __shfl_xor(sx1[j],32,64);
  }
  float* partT = (float*)(smem + PTo);    // [4 wv][2 img][64 d]
  float* partX = (float*)(smem + PXo);
  float* xsumL = (float*)(smem + XSo);    // [2 img][64 d]
  float* tsumL = (float*)(smem + TSUML);  // [2 img][64 d]
  float* sqsL  = (float*)(smem + SQSL);   // [2 img][64 d]
  if (lq == 0){
    #pragma unroll
    for (int j=0;j<4;j++){
      partT[wv*128 +       j*16+lr] = st0[j];
      partT[wv*128 + 64  + j*16+lr] = st1[j];
      partX[wv*128 +       j*16+lr] = sx0[j];
      partX[wv*128 + 64  + j*16+lr] = sx1[j];
    }
  }
  __syncthreads();
  if (tid < 128){
    int im = tid >> 6, d = tid & 63;
    float tt = partT[im*64+d] + partT[128+im*64+d] + partT[256+im*64+d] + partT[384+im*64+d];
    float xx = partX[im*64+d] + partX[128+im*64+d] + partX[256+im*64+d] + partX[384+im*64+d];
    float clsv = cls_tok[d] + pos_emb[d];
    float c1v = clsv, c2v = clsv*clsv;
    #pragma unroll
    for (int off=1; off<64; off<<=1){ c1v += __shfl_xor(c1v, off, 64); c2v += __shfl_xor(c2v, off, 64); }
    float cm = c1v*(1.f/64.f), cv = c2v*(1.f/64.f) - cm*cm;
    float cxn = (clsv - cm)*rsqrtf(cv + 1e-5f)*ln1_g[d] + ln1_b[d];
    *(u16*)(smem + im*12288 + d*2) = f2bf(cxn);     // xnL row 0 (swizzle term 0)
    tsumL[im*64 + d] = tt + clsv;
    xsumL[im*64 + d] = (xx + cxn) * (1.f/82.f);
  }
  __syncthreads();
  {
    int im = tid >> 7, d2 = tid & 127;
    int d = d2 >> 1, half = d2 & 1;
    float a = 0.f;
    int k0 = half*32;
    #pragma unroll
    for (int k=0;k<32;k++) a = fmaf(xsumL[im*64 + k0+k], Wst[(k0+k)*64+d], a);
    a += __shfl_xor(a, 1, 64);
    if (half == 0){
      a += bst[d];
      a = fmaxf(a, 0.f);
      a = 1.f/(1.f + __expf(-a));
      sqsL[im*64 + d] = a + bias_st[d];
    }
  }
  __syncthreads();   // xnL / tsumL / sqsL complete

  // ---- fused token mixer (k_fuse logic, per image) ----
  // B-frags (im-invariant): cc = wv*16+lr for each of Wb/Wc/Wd
  bf16x8 bfr[3][2];
  {
    int cc = wv*16 + lr;
    const float* Ws[3] = {Wb, Wc, Wd};
    #pragma unroll
    for (int w=0;w<3;w++)
      #pragma unroll
      for (int kk=0;kk<2;kk++){
        int k0 = kk*32 + lq*8;
        bf16x8 f;
        #pragma unroll
        for (int e=0;e<8;e++) f[e] = (short)f2bf(Ws[w][(k0+e)*64 + cc]);
        bfr[w][kk] = f;
      }
  }
  u16* AxL = (u16*)(smem + AXo);
  u16* BxL = (u16*)(smem + BXo);
  u16* CxL = (u16*)(smem + CXo);

  for (int im = 0; im < 2; im++){
    const char* xb = smem + im*12288;
    f32x4 facc[6][3];
    #pragma unroll
    for (int i=0;i<6;i++)
      #pragma unroll
      for (int w=0;w<3;w++) facc[i][w] = (f32x4){0.f,0.f,0.f,0.f};

    #pragma unroll
    for (int rt=0;rt<6;rt++){
      int row = rt*16 + lr;
      bf16x8 afr[2];
      #pragma unroll
      for (int kk=0;kk<2;kk++)
        afr[kk] = *(const bf16x8*)(xb + row*128 + ((kk*64 + lq*16) ^ ((row&7)<<4)));
      #pragma unroll
      for (int kk=0;kk<2;kk++)
        #pragma unroll
        for (int w=0;w<3;w++)
          facc[rt][w] = __builtin_amdgcn_mfma_f32_16x16x32_bf16(afr[kk], bfr[w][kk], facc[rt][w], 0, 0, 0);
    }

    {
      int d = wv*16 + lr;
      float bB = bbv[d], bC = bcv[d], bD = bdv[d];
      #pragma unroll
      for (int rt=0;rt<6;rt++){
        #pragma unroll
        for (int e=0;e<4;e++){
          int t = rt*16 + lq*4 + e;
          if (t < 82){
            float B0 = facc[rt][0][e] + bB;
            float Cv = facc[rt][1][e] + bC;
            float Dr = facc[rt][2][e] + bD + delta_p[t*64+d];
            float D  = 1.f/(1.f + __expf(-Dr));
            float xv = bf2f(*(const u16*)(xb + t*128 + ((d*2) ^ ((t&7)<<4))));
            AxL[t*66+d] = f2bf(D * A_p[t*64+d]);
            BxL[t*66+d] = f2bf(D * B0 * xv);
            CxL[t*66+d] = f2bf(Cv);
          }
        }
      }
    }
    __syncthreads();

    if (wv == 0){
      int d = ln;
      float sq = sqsL[im*64 + d];
      float s = 0.f, racc = 0.f;
      for (int t = 0; t < 82; t++){
        float a  = bf2f(AxL[t*66+d]);
        float bx = bf2f(BxL[t*66+d]);
        float c  = bf2f(CxL[t*66+d]);
        float xv = bf2f(*(const u16*)(xb + t*128 + ((d*2) ^ ((t&7)<<4))));
        s = fmaf(a, s, bx);
        float o = fmaf(c, s, sq*xv);
        float z = 1.f/(1.f + __expf(-xv));
        racc = fmaf(o, z, racc);
      }
      float pooled = (tsumL[im*64 + d] + racc) * (1.f/82.f);
      float s1 = pooled, s2v = pooled*pooled;
      #pragma unroll
      for (int off=32; off>0; off>>=1){ s1 += __shfl_xor(s1, off, 64); s2v += __shfl_xor(s2v, off, 64); }
      float mean = s1*(1.f/64.f), var = s2v*(1.f/64.f) - mean*mean;
      float yn = (pooled - mean)*rsqrtf(var + 1e-5f)*ln2_g[d] + ln2_b[d];
      float a1 = bm1[d];
      for (int k=0;k<64;k++) a1 = fmaf(__shfl(yn, k, 64), Wm1[k*64+d], a1);
      float hg = 0.5f*a1*(1.f + erff(a1*0.70710678118654752f));
      float a2 = bm2[d];
      for (int k=0;k<64;k++) a2 = fmaf(__shfl(hg, k, 64), Wm2[k*64+d], a2);
      out[(size_t)(img0+im)*64 + d] = pooled + a2;
    }
    __syncthreads();   // AxL/BxL/CxL reads done before im=1 overwrites
  }
}

extern "C" void kernel_launch(void* const* d_in, const int* in_sizes, int n_in,
                              void* d_out, int out_size, void* d_ws, size_t ws_size,
                              hipStream_t stream){
  const float* x       = (const float*)d_in[0];
  const float* w3      = (const float*)d_in[1];
  const float* b3      = (const float*)d_in[2];
  const float* g3      = (const float*)d_in[3];
  const float* be3     = (const float*)d_in[4];
  const float* m3      = (const float*)d_in[5];
  const float* v3      = (const float*)d_in[6];
  const float* w2c     = (const float*)d_in[7];
  const float* b2c     = (const float*)d_in[8];
  const float* g2      = (const float*)d_in[9];
  const float* be2     = (const float*)d_in[10];
  const float* m2      = (const float*)d_in[11];
  const float* v2      = (const float*)d_in[12];
  const float* pos_emb = (const float*)d_in[13];
  const float* cls_tok = (const float*)d_in[14];
  const float* ln1_g   = (const float*)d_in[15];
  const float* ln1_b   = (const float*)d_in[16];
  const float* Wb      = (const float*)d_in[17];
  const float* bbv     = (const float*)d_in[18];
  const float* Wc      = (const float*)d_in[19];
  const float* bc      = (const float*)d_in[20];
  const float* Wd      = (const float*)d_in[21];
  const float* bd      = (const float*)d_in[22];
  const float* delta_p = (const float*)d_in[23];
  const float* A_p     = (const float*)d_in[24];
  const float* Wst     = (const float*)d_in[25];
  const float* bst     = (const float*)d_in[26];
  const float* bias_st = (const float*)d_in[27];
  const float* ln2_g   = (const float*)d_in[28];
  const float* ln2_b   = (const float*)d_in[29];
  const float* Wm1     = (const float*)d_in[30];
  const float* bm1     = (const float*)d_in[31];
  const float* Wm2     = (const float*)d_in[32];
  const float* bm2     = (const float*)d_in[33];

  // workspace layout (bytes), peak = 159,547,392:
  //   h1   [0,          159252480)  (conv3d -> conv2d)
  //   Wt2  [159252480,  159547392)  (conv3d wt-blocks -> conv2d)
  char* ws = (char*)d_ws;
  u16*   h1   = (u16*)ws;
  u16*   Wt2  = (u16*)(ws + 159252480);

  k_conv3d<<<4672, 256, 0, stream>>>(x, w3, b3, g3, be3, m3, v3,
                                     w2c, g2, v2, h1, Wt2);
  k_conv2d<<<2048, 256, 0, stream>>>(h1, Wt2, b2c, g2, be2, m2, v2,
                                     pos_emb, cls_tok, ln1_g, ln1_b,
                                     Wst, bst, bias_st,
                                     Wb, Wc, Wd, bbv, bc, bd, delta_p, A_p,
                                     ln2_g, ln2_b, Wm1, bm1, Wm2, bm2,
                                     (float*)d_out);
}

// Round 21
// 333.012 us; speedup vs baseline: 1.8259x; 1.0862x over previous
//
#include <hip/hip_runtime.h>

typedef unsigned short u16;
typedef unsigned int u32;
typedef __attribute__((ext_vector_type(8))) short bf16x8;
typedef __attribute__((ext_vector_type(4))) float f32x4;
typedef __attribute__((ext_vector_type(4))) int i32x4;

#define DEV __device__ __forceinline__

DEV u16 f2bf(float f){
  unsigned u = __float_as_uint(f);
  u += 0x7fffu + ((u >> 16) & 1u);
  return (u16)(u >> 16);
}
DEV float bf2f(u16 h){ return __uint_as_float(((unsigned)h) << 16); }

// Inverse spiral map: pixel index (0..80) -> spiral token position (0..80).
DEV int spiral_t(int pix){
  int px = pix / 9, py = pix % 9;
  int dr = px - 4, dc = py - 4;
  int ar = dr < 0 ? -dr : dr, ac = dc < 0 ? -dc : dc;
  int r = ar > ac ? ar : ac;
  if (r == 0) return 0;
  int start = 1 + 4*r*(r-1);
  if (dr == -r && dc >= -r+1) return start + dc + r - 1;
  if (dc == r)  return start + 2*r + dr + r - 1;
  if (dr == r)  return start + 4*r + dc + r;
  return start + 6*r + dr + r;
}

// ---------------- conv3d (1->8, k=3^3, SAME) + BN + ReLU -> h1 bf16 [B][81][240]
// v3 (round-17): thread owns a (pix,co) column; 27 weights in VGPRs; dd-sliding
// 3-slice register window; 30 outputs -> 15 dword stores.
// MERGED: blocks >= 4096 run the k_wt transform (Wt2 prep).
__global__ __launch_bounds__(256) void k_conv3d(const float* __restrict__ x,
    const float* __restrict__ w3, const float* __restrict__ b3,
    const float* __restrict__ g3, const float* __restrict__ be3,
    const float* __restrict__ m3, const float* __restrict__ v3,
    const float* __restrict__ w2c, const float* __restrict__ g2,
    const float* __restrict__ v2,
    u16* __restrict__ h1, u16* __restrict__ Wt2){
  __shared__ float tile[3993];   // 33 slices x 121 ([dd+1][px+1][py+1], zero-padded)
  __shared__ float wle[216];
  __shared__ float sc[8], sh[8];
  int b = blockIdx.x, tid = threadIdx.x;

  if (b >= 4096){                // ---- wt blocks ----
    int idx = (b - 4096)*256 + tid;
    int kk = idx & 31;
    int o  = (idx >> 5) & 63;
    int tile2 = idx >> 11;        // 0..71
    int dxy = tile2 >> 3;
    int chunk = tile2 & 7;
    int ch = chunk*32 + kk;
    float v = 0.f;
    if (ch < 240){
      float s2 = g2[o] * rsqrtf(v2[o] + 1e-5f);
      v = w2c[(o*240 + ch)*9 + dxy] * s2;
    }
    Wt2[idx] = f2bf(v);
    return;
  }

  for (int i = tid; i < 3993; i += 256) tile[i] = 0.f;
  if (tid < 216) wle[tid] = w3[tid];
  if (tid < 8){
    float s = g3[tid]*rsqrtf(v3[tid]+1e-5f);
    sc[tid] = s;
    sh[tid] = (b3[tid]-m3[tid])*s + be3[tid];
  }
  __syncthreads();
  const float* xin = x + b*2430;
  for (int i = tid; i < 2430; i += 256){
    int dd = i / 81, rem = i % 81;
    int px = rem / 9, py = rem % 9;
    tile[(dd+1)*121 + (px+1)*11 + (py+1)] = xin[i];
  }
  __syncthreads();
  u16* hb = h1 + (size_t)b*19440;

  for (int col = tid; col < 648; col += 256){
    int pix = col >> 3, co = col & 7;
    int px = pix / 9, py = pix % 9;
    const float* base = tile + px*11 + py;     // slice s at base + s*121
    float wp[27];
    #pragma unroll
    for (int q=0;q<27;q++) wp[q] = wle[co*27+q];
    float scv = sc[co], shv = sh[co];

    float s0[9], s1[9], s2[9];
#define LSL(S, SL)                                                            \
    { const float* tp2 = base + (SL)*121;                                     \
      _Pragma("unroll")                                                       \
      for (int kx=0;kx<3;kx++)                                                \
        _Pragma("unroll")                                                     \
        for (int ky=0;ky<3;ky++) S[kx*3+ky] = tp2[kx*11+ky]; }
#define DOT3(A, SA, SB, SC)                                                   \
    { A = 0.f;                                                                \
      _Pragma("unroll")                                                       \
      for (int q=0;q<9;q++) A = fmaf(SA[q], wp[q], A);                        \
      _Pragma("unroll")                                                       \
      for (int q=0;q<9;q++) A = fmaf(SB[q], wp[9+q], A);                      \
      _Pragma("unroll")                                                       \
      for (int q=0;q<9;q++) A = fmaf(SC[q], wp[18+q], A); }

    LSL(s0, 0); LSL(s1, 1); LSL(s2, 2);
    u16 outv[30];
    #pragma unroll
    for (int d3 = 0; d3 < 30; d3 += 3){
      float a;
      DOT3(a, s0, s1, s2);
      outv[d3] = f2bf(fmaxf(fmaf(a, scv, shv), 0.f));
      LSL(s0, d3+3);
      DOT3(a, s1, s2, s0);
      outv[d3+1] = f2bf(fmaxf(fmaf(a, scv, shv), 0.f));
      LSL(s1, d3+4);
      DOT3(a, s2, s0, s1);
      outv[d3+2] = f2bf(fmaxf(fmaf(a, scv, shv), 0.f));
      LSL(s2, d3+5);                 // max slice index 32 -> in-bounds (33 slices)
    }
#undef LSL
#undef DOT3
    u32* dst = (u32*)(hb + pix*240 + co*30);
    #pragma unroll
    for (int q=0;q<15;q++) dst[q] = ((u32)outv[2*q+1] << 16) | (u32)outv[2*q];
  }
}

// ---------------- conv2d MFMA GEMM + BN + ReLU + pos_emb + LN1/tsum/SToken
//                  + FUSED token mixer (B/C/delta GEMM + S6 scan + LN2 + MLP)
// v12: v11 + wave-parallel S6 scan. The affine recurrence s=a*s+bx is split
// into 4 segments (21/21/21/19); pass A computes per-segment (P=prod a, Q);
// LDS prefix-compose gives each wave its s_start; pass B replays exactly.
// LN2+MLP for both images run in parallel (waves 0/1) after the im-loop.
__global__ __launch_bounds__(256, 2) void k_conv2d(const u16* __restrict__ h1,
    const u16* __restrict__ Wt2,
    const float* __restrict__ b2c, const float* __restrict__ g2,
    const float* __restrict__ be2, const float* __restrict__ m2,
    const float* __restrict__ v2,
    const float* __restrict__ pos_emb, const float* __restrict__ cls_tok,
    const float* __restrict__ ln1_g, const float* __restrict__ ln1_b,
    const float* __restrict__ Wst, const float* __restrict__ bst,
    const float* __restrict__ bias_st,
    const float* __restrict__ Wb, const float* __restrict__ Wc,
    const float* __restrict__ Wd,
    const float* __restrict__ bbv, const float* __restrict__ bcv,
    const float* __restrict__ bdv,
    const float* __restrict__ delta_p, const float* __restrict__ A_p,
    const float* __restrict__ ln2_g, const float* __restrict__ ln2_b,
    const float* __restrict__ Wm1, const float* __restrict__ bm1,
    const float* __restrict__ Wm2, const float* __restrict__ bm2,
    float* __restrict__ out){
  // GEMM phase: rows r in [0,162) at r*496; zrow at 80352.
  // Fuse phase (smem reuse): xnL [2][96][128B] at 0; tsumL f32[128] at 24576;
  //   sqsL f32[128] at 25088; AxL/BxL/CxL u16[96*66] at 25600/38272/50944;
  //   RCl [2 im][4 seg][64] f32 at 63616 (2KB); PQl [4 seg][2][64] f32 at
  //   65664 (2KB, per-image reuse); xsumL at 67712 (512B).
  __shared__ __align__(16) char smem[80848];
  const int ZROW = 80352;
  const int TSUML = 24576, SQSL = 25088, AXo = 25600, BXo = 38272, CXo = 50944;
  const int PTo = 63616, PXo = 65664, XSo = 67712;
  int tid = threadIdx.x;
  int wv = tid >> 6, ln = tid & 63;
  int lq = ln >> 4, lr = ln & 15;
  int img0 = blockIdx.x*2;
  size_t grow0 = (size_t)img0*81;

  int bln = lr*32 + lq*8;    // u16 offset of this lane's B-frag within a [64o][32k] tile

#define LOADB(TAP, C, B)                                                        \
    { const u16* Bt_ = Wt2 + (TAP)*16384 + bln;                                 \
      _Pragma("unroll")                                                         \
      for (int kk=0;kk<2;kk++)                                                  \
        _Pragma("unroll")                                                       \
        for (int j=0;j<4;j++)                                                   \
          B[kk][j] = *(const bf16x8*)(Bt_ + ((C)*2+kk)*2048 + j*512); }

  // B prologue (tap0 chunks 0,1,2) issued BEFORE the barrier
  bf16x8 bB0[2][4], bB1[2][4], bB2[2][4];
  LOADB(0, 0, bB0);
  LOADB(0, 1, bB1);
  LOADB(0, 2, bB2);

  for (int r = tid; r < 162; r += 256)
    *(i32x4*)(smem + r*496 + 480) = (i32x4){0,0,0,0};
  if (tid < 31) *(i32x4*)(smem + ZROW + tid*16) = (i32x4){0,0,0,0};
  {
    const u16* src = h1 + grow0*240;
    for (int idx = tid; idx < 162*30; idx += 256){
      int r = idx / 30, c = idx % 30;
      *(i32x4*)(smem + r*496 + c*16) = *(const i32x4*)(src + idx*8);
    }
  }
  __syncthreads();

  f32x4 acc[3][4];
  #pragma unroll
  for (int i=0;i<3;i++)
    #pragma unroll
    for (int j=0;j<4;j++) acc[i][j] = (f32x4){0.f,0.f,0.f,0.f};

#define CALCADDR(TAP, A0, A1, A13)                                              \
  { int dx = (TAP)/3 - 1, dy = (TAP)%3 - 1;                                     \
    _Pragma("unroll")                                                           \
    for (int rt=0;rt<3;rt++){                                                   \
      int row = (wv*3+rt)*16 + lr;                                              \
      int pix = row % 81;                                                       \
      int px = pix/9, py = pix%9;                                               \
      int px2 = px + dx, py2 = py + dy;                                         \
      bool valid = (row < 162) && ((unsigned)px2 < 9u) && ((unsigned)py2 < 9u); \
      int nrow = (row - pix) + px2*9 + py2;                                     \
      int base = valid ? nrow*496 : ZROW;                                       \
      A0[rt]  = base + lq*16;                                                   \
      A1[rt]  = base + 64 + lq*16;                                              \
      A13[rt] = (lq == 3) ? ZROW : (A1[rt] + 384);                              \
    } }

#define LOADA(C, SA0, SA1, SA13, A0, A1)                                        \
    { _Pragma("unroll")                                                         \
      for (int rt=0;rt<3;rt++){                                                 \
        A0[rt] = *(const bf16x8*)(smem + SA0[rt] + (C)*128);                    \
        A1[rt] = *(const bf16x8*)(smem + ((C)==3 ? SA13[rt]                     \
                                                 : SA1[rt] + (C)*128)); } }

#define DOMFMA(B, A0, A1)                                                       \
    { __builtin_amdgcn_s_setprio(1);                                            \
      _Pragma("unroll")                                                         \
      for (int rt=0;rt<3;rt++)                                                  \
        _Pragma("unroll")                                                       \
        for (int j=0;j<4;j++)                                                   \
          acc[rt][j] = __builtin_amdgcn_mfma_f32_16x16x32_bf16(A0[rt], B[0][j], acc[rt][j], 0, 0, 0); \
      _Pragma("unroll")                                                         \
      for (int rt=0;rt<3;rt++)                                                  \
        _Pragma("unroll")                                                       \
        for (int j=0;j<4;j++)                                                   \
          acc[rt][j] = __builtin_amdgcn_mfma_f32_16x16x32_bf16(A1[rt], B[1][j], acc[rt][j], 0, 0, 0); \
      __builtin_amdgcn_s_setprio(0); }

#define TAPBODY(TAPV, BA, BB, BC)                                               \
  { int ntap_ = (TAPV) < 8 ? (TAPV)+1 : 8;                                      \
    DOMFMA(BA, aAX0, aAX1);                                                     \
    LOADB((TAPV), 3, BA); LOADA(2, aC0, aC1, aC13, aAX0, aAX1);                 \
    DOMFMA(BB, aAY0, aAY1);                                                     \
    LOADB(ntap_, 0, BB); CALCADDR(ntap_, aN0, aN1, aN13);                       \
    LOADA(3, aC0, aC1, aC13, aAY0, aAY1);                                       \
    DOMFMA(BC, aAX0, aAX1);                                                     \
    LOADB(ntap_, 1, BC); LOADA(0, aN0, aN1, aN13, aAX0, aAX1);                  \
    DOMFMA(BA, aAY0, aAY1);                                                     \
    LOADB(ntap_, 2, BA); LOADA(1, aN0, aN1, aN13, aAY0, aAY1);                  \
    _Pragma("unroll")                                                           \
    for (int rt=0;rt<3;rt++){ aC0[rt]=aN0[rt]; aC1[rt]=aN1[rt]; aC13[rt]=aN13[rt]; } }

  int aC0[3], aC1[3], aC13[3];
  int aN0[3], aN1[3], aN13[3];
  bf16x8 aAX0[3], aAX1[3], aAY0[3], aAY1[3];

  CALCADDR(0, aC0, aC1, aC13);
  LOADA(0, aC0, aC1, aC13, aAX0, aAX1);
  LOADA(1, aC0, aC1, aC13, aAY0, aAY1);

  for (int t3 = 0; t3 < 9; t3 += 3){
    TAPBODY(t3+0, bB0, bB1, bB2);
    TAPBODY(t3+1, bB1, bB2, bB0);
    TAPBODY(t3+2, bB2, bB0, bB1);
  }
#undef CALCADDR
#undef LOADB
#undef LOADA
#undef DOMFMA
#undef TAPBODY

  __syncthreads();   // all image-LDS reads done; smem reusable

  // zero xnL rows 82..95 for both images
  if (tid < 224){
    int im = tid / 112, r2 = tid % 112;
    int rr = 82 + (r2 >> 3), c = r2 & 7;
    *(i32x4*)(smem + im*12288 + rr*128 + ((c*16) ^ ((rr&7)<<4))) = (i32x4){0,0,0,0};
  }

  float t2c[4], lg[4], lb[4];
  #pragma unroll
  for (int j=0;j<4;j++){
    int col = j*16 + lr;
    float s2 = g2[col]*rsqrtf(v2[col]+1e-5f);
    t2c[j] = (b2c[col]-m2[col])*s2 + be2[col];
    lg[j] = ln1_g[col]; lb[j] = ln1_b[col];
  }

  float st0[4]={0,0,0,0}, st1[4]={0,0,0,0};
  float sx0[4]={0,0,0,0}, sx1[4]={0,0,0,0};

  #pragma unroll
  for (int rt=0;rt<3;rt++){
    #pragma unroll
    for (int e=0;e<4;e++){
      int row = (wv*3+rt)*16 + lq*4 + e;
      if (row < 162){
        int im = (row >= 81);
        int pix = row - im*81;
        int tsp = spiral_t(pix);
        const float* pe = pos_emb + (1+tsp)*64;
        float y[4], m1 = 0.f, m2v = 0.f;
        #pragma unroll
        for (int j=0;j<4;j++){
          y[j] = fmaxf(acc[rt][j][e] + t2c[j], 0.f) + pe[j*16+lr];
          m1 += y[j]; m2v = fmaf(y[j], y[j], m2v);
        }
        #pragma unroll
        for (int off=1; off<16; off<<=1){
          m1  += __shfl_xor(m1,  off, 64);
          m2v += __shfl_xor(m2v, off, 64);
        }
        float mean = m1*(1.f/64.f);
        float var  = m2v*(1.f/64.f) - mean*mean;
        float rs = rsqrtf(var + 1e-5f);
        int trow = 1 + tsp;
        char* dl = smem + im*12288 + trow*128;
        int sz = (trow & 7) << 4;
        #pragma unroll
        for (int j=0;j<4;j++){
          float xnv = (y[j]-mean)*rs*lg[j] + lb[j];
          *(u16*)(dl + (((j*16+lr)*2) ^ sz)) = f2bf(xnv);
          if (im == 0){ st0[j] += y[j]; sx0[j] += xnv; }
          else        { st1[j] += y[j]; sx1[j] += xnv; }
        }
      }
    }
  }

  #pragma unroll
  for (int j=0;j<4;j++){
    st0[j] += __shfl_xor(st0[j],16,64); st0[j] += __shfl_xor(st0[j],32,64);
    st1[j] += __shfl_xor(st1[j],16,64); st1[j] += __shfl_xor(st1[j],32,64);
    sx0[j] += __shfl_xor(sx0[j],16,64); sx0[j] += __shfl_xor(sx0[j],32,64);
    sx1[j] += __shfl_xor(sx1[j],16,64); sx1[j] += __shfl_xor(sx1[j],32,64);
  }
  float* partT = (float*)(smem + PTo);    // [4 wv][2 img][64 d] (dead after LN1 combine)
  float* partX = (float*)(smem + PXo);
  float* xsumL = (float*)(smem + XSo);    // [2 img][64 d]
  float* tsumL = (float*)(smem + TSUML);  // [2 img][64 d]
  float* sqsL  = (float*)(smem + SQSL);   // [2 img][64 d]
  if (lq == 0){
    #pragma unroll
    for (int j=0;j<4;j++){
      partT[wv*128 +       j*16+lr] = st0[j];
      partT[wv*128 + 64  + j*16+lr] = st1[j];
      partX[wv*128 +       j*16+lr] = sx0[j];
      partX[wv*128 + 64  + j*16+lr] = sx1[j];
    }
  }
  __syncthreads();
  if (tid < 128){
    int im = tid >> 6, d = tid & 63;
    float tt = partT[im*64+d] + partT[128+im*64+d] + partT[256+im*64+d] + partT[384+im*64+d];
    float xx = partX[im*64+d] + partX[128+im*64+d] + partX[256+im*64+d] + partX[384+im*64+d];
    float clsv = cls_tok[d] + pos_emb[d];
    float c1v = clsv, c2v = clsv*clsv;
    #pragma unroll
    for (int off=1; off<64; off<<=1){ c1v += __shfl_xor(c1v, off, 64); c2v += __shfl_xor(c2v, off, 64); }
    float cm = c1v*(1.f/64.f), cv = c2v*(1.f/64.f) - cm*cm;
    float cxn = (clsv - cm)*rsqrtf(cv + 1e-5f)*ln1_g[d] + ln1_b[d];
    *(u16*)(smem + im*12288 + d*2) = f2bf(cxn);     // xnL row 0 (swizzle term 0)
    tsumL[im*64 + d] = tt + clsv;
    xsumL[im*64 + d] = (xx + cxn) * (1.f/82.f);
  }
  __syncthreads();
  {
    int im = tid >> 7, d2 = tid & 127;
    int d = d2 >> 1, half = d2 & 1;
    float a = 0.f;
    int k0 = half*32;
    #pragma unroll
    for (int k=0;k<32;k++) a = fmaf(xsumL[im*64 + k0+k], Wst[(k0+k)*64+d], a);
    a += __shfl_xor(a, 1, 64);
    if (half == 0){
      a += bst[d];
      a = fmaxf(a, 0.f);
      a = 1.f/(1.f + __expf(-a));
      sqsL[im*64 + d] = a + bias_st[d];
    }
  }
  __syncthreads();   // xnL / tsumL / sqsL complete

  // ---- fused token mixer ----
  // B-frags (im-invariant): cc = wv*16+lr for each of Wb/Wc/Wd
  bf16x8 bfr[3][2];
  {
    int cc = wv*16 + lr;
    const float* Ws[3] = {Wb, Wc, Wd};
    #pragma unroll
    for (int w=0;w<3;w++)
      #pragma unroll
      for (int kk=0;kk<2;kk++){
        int k0 = kk*32 + lq*8;
        bf16x8 f;
        #pragma unroll
        for (int e=0;e<8;e++) f[e] = (short)f2bf(Ws[w][(k0+e)*64 + cc]);
        bfr[w][kk] = f;
      }
  }
  u16* AxL = (u16*)(smem + AXo);
  u16* BxL = (u16*)(smem + BXo);
  u16* CxL = (u16*)(smem + CXo);
  float* RCl = (float*)(smem + PTo);   // [2 im][4 seg][64]  (partT dead)
  float* PQl = (float*)(smem + PXo);   // [4 seg][2][64]     (partX dead, per-im reuse)

  for (int im = 0; im < 2; im++){
    const char* xb = smem + im*12288;
    f32x4 facc[6][3];
    #pragma unroll
    for (int i=0;i<6;i++)
      #pragma unroll
      for (int w=0;w<3;w++) facc[i][w] = (f32x4){0.f,0.f,0.f,0.f};

    #pragma unroll
    for (int rt=0;rt<6;rt++){
      int row = rt*16 + lr;
      bf16x8 afr[2];
      #pragma unroll
      for (int kk=0;kk<2;kk++)
        afr[kk] = *(const bf16x8*)(xb + row*128 + ((kk*64 + lq*16) ^ ((row&7)<<4)));
      #pragma unroll
      for (int kk=0;kk<2;kk++)
        #pragma unroll
        for (int w=0;w<3;w++)
          facc[rt][w] = __builtin_amdgcn_mfma_f32_16x16x32_bf16(afr[kk], bfr[w][kk], facc[rt][w], 0, 0, 0);
    }

    {
      int d = wv*16 + lr;
      float bB = bbv[d], bC = bcv[d], bD = bdv[d];
      #pragma unroll
      for (int rt=0;rt<6;rt++){
        #pragma unroll
        for (int e=0;e<4;e++){
          int t = rt*16 + lq*4 + e;
          if (t < 82){
            float B0 = facc[rt][0][e] + bB;
            float Cv = facc[rt][1][e] + bC;
            float Dr = facc[rt][2][e] + bD + delta_p[t*64+d];
            float D  = 1.f/(1.f + __expf(-Dr));
            float xv = bf2f(*(const u16*)(xb + t*128 + ((d*2) ^ ((t&7)<<4))));
            AxL[t*66+d] = f2bf(D * A_p[t*64+d]);
            BxL[t*66+d] = f2bf(D * B0 * xv);
            CxL[t*66+d] = f2bf(Cv);
          }
        }
      }
    }
    __syncthreads();

    // pass A: per-segment affine composition (P, Q) -- wave wv owns
    // timesteps [21*wv, 21*wv+21) (last segment 19)
    {
      int d = ln;
      int S = wv*21, E = (wv==3) ? 82 : S+21;
      float P = 1.f, Q = 0.f;
      for (int t = S; t < E; t++){
        float a  = bf2f(AxL[t*66+d]);
        float bx = bf2f(BxL[t*66+d]);
        Q = fmaf(a, Q, bx);
        P *= a;
      }
      PQl[(wv*2+0)*64 + d] = P;
      PQl[(wv*2+1)*64 + d] = Q;
    }
    __syncthreads();
    // prefix-compose s_start, then pass B: exact sequential replay + racc
    {
      int d = ln;
      int S = wv*21, E = (wv==3) ? 82 : S+21;
      float s = 0.f;
      #pragma unroll
      for (int w2 = 0; w2 < 3; w2++)
        if (w2 < wv)
          s = fmaf(PQl[(w2*2+0)*64 + d], s, PQl[(w2*2+1)*64 + d]);
      float sq = sqsL[im*64 + d];
      float racc = 0.f;
      for (int t = S; t < E; t++){
        float a  = bf2f(AxL[t*66+d]);
        float bx = bf2f(BxL[t*66+d]);
        float c  = bf2f(CxL[t*66+d]);
        float xv = bf2f(*(const u16*)(xb + t*128 + ((d*2) ^ ((t&7)<<4))));
        s = fmaf(a, s, bx);
        float o = fmaf(c, s, sq*xv);
        float z = 1.f/(1.f + __expf(-xv));
        racc = fmaf(o, z, racc);
      }
      RCl[im*256 + wv*64 + d] = racc;
    }
    __syncthreads();   // RC done; AxL/BxL/CxL free for next image
  }

  // final: pooled + LN2 + MLP for both images in parallel (waves 0 and 1)
  if (tid < 128){
    int im = wv, d = ln;
    float racc = RCl[im*256 + d] + RCl[im*256 + 64 + d]
               + RCl[im*256 + 128 + d] + RCl[im*256 + 192 + d];
    float pooled = (tsumL[im*64 + d] + racc) * (1.f/82.f);
    float s1 = pooled, s2v = pooled*pooled;
    #pragma unroll
    for (int off=32; off>0; off>>=1){ s1 += __shfl_xor(s1, off, 64); s2v += __shfl_xor(s2v, off, 64); }
    float mean = s1*(1.f/64.f), var = s2v*(1.f/64.f) - mean*mean;
    float yn = (pooled - mean)*rsqrtf(var + 1e-5f)*ln2_g[d] + ln2_b[d];
    float a1 = bm1[d];
    for (int k=0;k<64;k++) a1 = fmaf(__shfl(yn, k, 64), Wm1[k*64+d], a1);
    float hg = 0.5f*a1*(1.f + erff(a1*0.70710678118654752f));
    float a2 = bm2[d];
    for (int k=0;k<64;k++) a2 = fmaf(__shfl(hg, k, 64), Wm2[k*64+d], a2);
    out[(size_t)(img0+im)*64 + d] = pooled + a2;
  }
}

extern "C" void kernel_launch(void* const* d_in, const int* in_sizes, int n_in,
                              void* d_out, int out_size, void* d_ws, size_t ws_size,
                              hipStream_t stream){
  const float* x       = (const float*)d_in[0];
  const float* w3      = (const float*)d_in[1];
  const float* b3      = (const float*)d_in[2];
  const float* g3      = (const float*)d_in[3];
  const float* be3     = (const float*)d_in[4];
  const float* m3      = (const float*)d_in[5];
  const float* v3      = (const float*)d_in[6];
  const float* w2c     = (const float*)d_in[7];
  const float* b2c     = (const float*)d_in[8];
  const float* g2      = (const float*)d_in[9];
  const float* be2     = (const float*)d_in[10];
  const float* m2      = (const float*)d_in[11];
  const float* v2      = (const float*)d_in[12];
  const float* pos_emb = (const float*)d_in[13];
  const float* cls_tok = (const float*)d_in[14];
  const float* ln1_g   = (const float*)d_in[15];
  const float* ln1_b   = (const float*)d_in[16];
  const float* Wb      = (const float*)d_in[17];
  const float* bbv     = (const float*)d_in[18];
  const float* Wc      = (const float*)d_in[19];
  const float* bc      = (const float*)d_in[20];
  const float* Wd      = (const float*)d_in[21];
  const float* bd      = (const float*)d_in[22];
  const float* delta_p = (const float*)d_in[23];
  const float* A_p     = (const float*)d_in[24];
  const float* Wst     = (const float*)d_in[25];
  const float* bst     = (const float*)d_in[26];
  const float* bias_st = (const float*)d_in[27];
  const float* ln2_g   = (const float*)d_in[28];
  const float* ln2_b   = (const float*)d_in[29];
  const float* Wm1     = (const float*)d_in[30];
  const float* bm1     = (const float*)d_in[31];
  const float* Wm2     = (const float*)d_in[32];
  const float* bm2     = (const float*)d_in[33];

  // workspace layout (bytes), peak = 159,547,392:
  //   h1   [0,          159252480)  (conv3d -> conv2d)
  //   Wt2  [159252480,  159547392)  (conv3d wt-blocks -> conv2d)
  char* ws = (char*)d_ws;
  u16*   h1   = (u16*)ws;
  u16*   Wt2  = (u16*)(ws + 159252480);

  k_conv3d<<<4672, 256, 0, stream>>>(x, w3, b3, g3, be3, m3, v3,
                                     w2c, g2, v2, h1, Wt2);
  k_conv2d<<<2048, 256, 0, stream>>>(h1, Wt2, b2c, g2, be2, m2, v2,
                                     pos_emb, cls_tok, ln1_g, ln1_b,
                                     Wst, bst, bias_st,
                                     Wb, Wc, Wd, bbv, bc, bd, delta_p, A_p,
                                     ln2_g, ln2_b, Wm1, bm1, Wm2, bm2,
                                     (float*)d_out);
}

// Round 22
// 330.098 us; speedup vs baseline: 1.8420x; 1.0088x over previous
//
#include <hip/hip_runtime.h>

typedef unsigned short u16;
typedef unsigned int u32;
typedef __attribute__((ext_vector_type(8))) short bf16x8;
typedef __attribute__((ext_vector_type(4))) float f32x4;
typedef __attribute__((ext_vector_type(4))) int i32x4;

#define DEV __device__ __forceinline__

DEV u16 f2bf(float f){
  unsigned u = __float_as_uint(f);
  u += 0x7fffu + ((u >> 16) & 1u);
  return (u16)(u >> 16);
}
DEV float bf2f(u16 h){ return __uint_as_float(((unsigned)h) << 16); }

// Inverse spiral map: pixel index (0..80) -> spiral token position (0..80).
DEV int spiral_t(int pix){
  int px = pix / 9, py = pix % 9;
  int dr = px - 4, dc = py - 4;
  int ar = dr < 0 ? -dr : dr, ac = dc < 0 ? -dc : dc;
  int r = ar > ac ? ar : ac;
  if (r == 0) return 0;
  int start = 1 + 4*r*(r-1);
  if (dr == -r && dc >= -r+1) return start + dc + r - 1;
  if (dc == r)  return start + 2*r + dr + r - 1;
  if (dr == r)  return start + 4*r + dc + r;
  return start + 6*r + dr + r;
}

// ---------------- conv3d (1->8, k=3^3, SAME) + BN + ReLU -> h1 bf16 [B][81][240]
// v3: thread owns a (pix,co) column; 27 weights in VGPRs; dd-sliding 3-slice
// register window; 30 outputs -> 15 dword stores.
// MERGED: blocks >= 4096 run the k_wt transform (Wt2 prep).
__global__ __launch_bounds__(256) void k_conv3d(const float* __restrict__ x,
    const float* __restrict__ w3, const float* __restrict__ b3,
    const float* __restrict__ g3, const float* __restrict__ be3,
    const float* __restrict__ m3, const float* __restrict__ v3,
    const float* __restrict__ w2c, const float* __restrict__ g2,
    const float* __restrict__ v2,
    u16* __restrict__ h1, u16* __restrict__ Wt2){
  __shared__ float tile[3993];   // 33 slices x 121 ([dd+1][px+1][py+1], zero-padded)
  __shared__ float wle[216];
  __shared__ float sc[8], sh[8];
  int b = blockIdx.x, tid = threadIdx.x;

  if (b >= 4096){                // ---- wt blocks ----
    int idx = (b - 4096)*256 + tid;
    int kk = idx & 31;
    int o  = (idx >> 5) & 63;
    int tile2 = idx >> 11;        // 0..71
    int dxy = tile2 >> 3;
    int chunk = tile2 & 7;
    int ch = chunk*32 + kk;
    float v = 0.f;
    if (ch < 240){
      float s2 = g2[o] * rsqrtf(v2[o] + 1e-5f);
      v = w2c[(o*240 + ch)*9 + dxy] * s2;
    }
    Wt2[idx] = f2bf(v);
    return;
  }

  for (int i = tid; i < 3993; i += 256) tile[i] = 0.f;
  if (tid < 216) wle[tid] = w3[tid];
  if (tid < 8){
    float s = g3[tid]*rsqrtf(v3[tid]+1e-5f);
    sc[tid] = s;
    sh[tid] = (b3[tid]-m3[tid])*s + be3[tid];
  }
  __syncthreads();
  const float* xin = x + b*2430;
  for (int i = tid; i < 2430; i += 256){
    int dd = i / 81, rem = i % 81;
    int px = rem / 9, py = rem % 9;
    tile[(dd+1)*121 + (px+1)*11 + (py+1)] = xin[i];
  }
  __syncthreads();
  u16* hb = h1 + (size_t)b*19440;

  for (int col = tid; col < 648; col += 256){
    int pix = col >> 3, co = col & 7;
    int px = pix / 9, py = pix % 9;
    const float* base = tile + px*11 + py;     // slice s at base + s*121
    float wp[27];
    #pragma unroll
    for (int q=0;q<27;q++) wp[q] = wle[co*27+q];
    float scv = sc[co], shv = sh[co];

    float s0[9], s1[9], s2[9];
#define LSL(S, SL)                                                            \
    { const float* tp2 = base + (SL)*121;                                     \
      _Pragma("unroll")                                                       \
      for (int kx=0;kx<3;kx++)                                                \
        _Pragma("unroll")                                                     \
        for (int ky=0;ky<3;ky++) S[kx*3+ky] = tp2[kx*11+ky]; }
#define DOT3(A, SA, SB, SC)                                                   \
    { A = 0.f;                                                                \
      _Pragma("unroll")                                                       \
      for (int q=0;q<9;q++) A = fmaf(SA[q], wp[q], A);                        \
      _Pragma("unroll")                                                       \
      for (int q=0;q<9;q++) A = fmaf(SB[q], wp[9+q], A);                      \
      _Pragma("unroll")                                                       \
      for (int q=0;q<9;q++) A = fmaf(SC[q], wp[18+q], A); }

    LSL(s0, 0); LSL(s1, 1); LSL(s2, 2);
    u16 outv[30];
    #pragma unroll
    for (int d3 = 0; d3 < 30; d3 += 3){
      float a;
      DOT3(a, s0, s1, s2);
      outv[d3] = f2bf(fmaxf(fmaf(a, scv, shv), 0.f));
      LSL(s0, d3+3);
      DOT3(a, s1, s2, s0);
      outv[d3+1] = f2bf(fmaxf(fmaf(a, scv, shv), 0.f));
      LSL(s1, d3+4);
      DOT3(a, s2, s0, s1);
      outv[d3+2] = f2bf(fmaxf(fmaf(a, scv, shv), 0.f));
      LSL(s2, d3+5);                 // max slice index 32 -> in-bounds (33 slices)
    }
#undef LSL
#undef DOT3
    u32* dst = (u32*)(hb + pix*240 + co*30);
    #pragma unroll
    for (int q=0;q<15;q++) dst[q] = ((u32)outv[2*q+1] << 16) | (u32)outv[2*q];
  }
}

// ---------------- conv2d MFMA GEMM + BN + ReLU + pos_emb + LN1/tsum/SToken
//                  + FUSED token mixer (B/C/delta GEMM + S6 scan + LN2 + MLP)
// v13: v12 + algebraic scan split. racc = sum((c*z)*s) + sq*sum(xv*z):
// z folded into stored Cz=bf16(Cv*z) at mixer-epilogue time; XZ=sum(xv*z)
// accumulated there too (shfl-reduced over lq, stored in dead xsumL). Pass B
// is now 3 LDS reads + 2 FMA per step -- no exp, no swizzled xv read.
__global__ __launch_bounds__(256, 2) void k_conv2d(const u16* __restrict__ h1,
    const u16* __restrict__ Wt2,
    const float* __restrict__ b2c, const float* __restrict__ g2,
    const float* __restrict__ be2, const float* __restrict__ m2,
    const float* __restrict__ v2,
    const float* __restrict__ pos_emb, const float* __restrict__ cls_tok,
    const float* __restrict__ ln1_g, const float* __restrict__ ln1_b,
    const float* __restrict__ Wst, const float* __restrict__ bst,
    const float* __restrict__ bias_st,
    const float* __restrict__ Wb, const float* __restrict__ Wc,
    const float* __restrict__ Wd,
    const float* __restrict__ bbv, const float* __restrict__ bcv,
    const float* __restrict__ bdv,
    const float* __restrict__ delta_p, const float* __restrict__ A_p,
    const float* __restrict__ ln2_g, const float* __restrict__ ln2_b,
    const float* __restrict__ Wm1, const float* __restrict__ bm1,
    const float* __restrict__ Wm2, const float* __restrict__ bm2,
    float* __restrict__ out){
  // GEMM phase: rows r in [0,162) at r*496; zrow at 80352.
  // Fuse phase (smem reuse): xnL [2][96][128B] at 0; tsumL f32[128] at 24576;
  //   sqsL f32[128] at 25088; AxL/BxL/CxL u16[96*66] at 25600/38272/50944;
  //   RCl [2 im][4 seg][64] f32 at 63616 (2KB); PQl [4 seg][2][64] f32 at
  //   65664 (2KB, per-image reuse); xsumL->XZl [2 im][64] at 67712 (512B).
  __shared__ __align__(16) char smem[80848];
  const int ZROW = 80352;
  const int TSUML = 24576, SQSL = 25088, AXo = 25600, BXo = 38272, CXo = 50944;
  const int PTo = 63616, PXo = 65664, XSo = 67712;
  int tid = threadIdx.x;
  int wv = tid >> 6, ln = tid & 63;
  int lq = ln >> 4, lr = ln & 15;
  int img0 = blockIdx.x*2;
  size_t grow0 = (size_t)img0*81;

  int bln = lr*32 + lq*8;    // u16 offset of this lane's B-frag within a [64o][32k] tile

#define LOADB(TAP, C, B)                                                        \
    { const u16* Bt_ = Wt2 + (TAP)*16384 + bln;                                 \
      _Pragma("unroll")                                                         \
      for (int kk=0;kk<2;kk++)                                                  \
        _Pragma("unroll")                                                       \
        for (int j=0;j<4;j++)                                                   \
          B[kk][j] = *(const bf16x8*)(Bt_ + ((C)*2+kk)*2048 + j*512); }

  // B prologue (tap0 chunks 0,1,2) issued BEFORE the barrier
  bf16x8 bB0[2][4], bB1[2][4], bB2[2][4];
  LOADB(0, 0, bB0);
  LOADB(0, 1, bB1);
  LOADB(0, 2, bB2);

  for (int r = tid; r < 162; r += 256)
    *(i32x4*)(smem + r*496 + 480) = (i32x4){0,0,0,0};
  if (tid < 31) *(i32x4*)(smem + ZROW + tid*16) = (i32x4){0,0,0,0};
  {
    const u16* src = h1 + grow0*240;
    for (int idx = tid; idx < 162*30; idx += 256){
      int r = idx / 30, c = idx % 30;
      *(i32x4*)(smem + r*496 + c*16) = *(const i32x4*)(src + idx*8);
    }
  }
  __syncthreads();

  f32x4 acc[3][4];
  #pragma unroll
  for (int i=0;i<3;i++)
    #pragma unroll
    for (int j=0;j<4;j++) acc[i][j] = (f32x4){0.f,0.f,0.f,0.f};

#define CALCADDR(TAP, A0, A1, A13)                                              \
  { int dx = (TAP)/3 - 1, dy = (TAP)%3 - 1;                                     \
    _Pragma("unroll")                                                           \
    for (int rt=0;rt<3;rt++){                                                   \
      int row = (wv*3+rt)*16 + lr;                                              \
      int pix = row % 81;                                                       \
      int px = pix/9, py = pix%9;                                               \
      int px2 = px + dx, py2 = py + dy;                                         \
      bool valid = (row < 162) && ((unsigned)px2 < 9u) && ((unsigned)py2 < 9u); \
      int nrow = (row - pix) + px2*9 + py2;                                     \
      int base = valid ? nrow*496 : ZROW;                                       \
      A0[rt]  = base + lq*16;                                                   \
      A1[rt]  = base + 64 + lq*16;                                              \
      A13[rt] = (lq == 3) ? ZROW : (A1[rt] + 384);                              \
    } }

#define LOADA(C, SA0, SA1, SA13, A0, A1)                                        \
    { _Pragma("unroll")                                                         \
      for (int rt=0;rt<3;rt++){                                                 \
        A0[rt] = *(const bf16x8*)(smem + SA0[rt] + (C)*128);                    \
        A1[rt] = *(const bf16x8*)(smem + ((C)==3 ? SA13[rt]                     \
                                                 : SA1[rt] + (C)*128)); } }

#define DOMFMA(B, A0, A1)                                                       \
    { __builtin_amdgcn_s_setprio(1);                                            \
      _Pragma("unroll")                                                         \
      for (int rt=0;rt<3;rt++)                                                  \
        _Pragma("unroll")                                                       \
        for (int j=0;j<4;j++)                                                   \
          acc[rt][j] = __builtin_amdgcn_mfma_f32_16x16x32_bf16(A0[rt], B[0][j], acc[rt][j], 0, 0, 0); \
      _Pragma("unroll")                                                         \
      for (int rt=0;rt<3;rt++)                                                  \
        _Pragma("unroll")                                                       \
        for (int j=0;j<4;j++)                                                   \
          acc[rt][j] = __builtin_amdgcn_mfma_f32_16x16x32_bf16(A1[rt], B[1][j], acc[rt][j], 0, 0, 0); \
      __builtin_amdgcn_s_setprio(0); }

#define TAPBODY(TAPV, BA, BB, BC)                                               \
  { int ntap_ = (TAPV) < 8 ? (TAPV)+1 : 8;                                      \
    DOMFMA(BA, aAX0, aAX1);                                                     \
    LOADB((TAPV), 3, BA); LOADA(2, aC0, aC1, aC13, aAX0, aAX1);                 \
    DOMFMA(BB, aAY0, aAY1);                                                     \
    LOADB(ntap_, 0, BB); CALCADDR(ntap_, aN0, aN1, aN13);                       \
    LOADA(3, aC0, aC1, aC13, aAY0, aAY1);                                       \
    DOMFMA(BC, aAX0, aAX1);                                                     \
    LOADB(ntap_, 1, BC); LOADA(0, aN0, aN1, aN13, aAX0, aAX1);                  \
    DOMFMA(BA, aAY0, aAY1);                                                     \
    LOADB(ntap_, 2, BA); LOADA(1, aN0, aN1, aN13, aAY0, aAY1);                  \
    _Pragma("unroll")                                                           \
    for (int rt=0;rt<3;rt++){ aC0[rt]=aN0[rt]; aC1[rt]=aN1[rt]; aC13[rt]=aN13[rt]; } }

  int aC0[3], aC1[3], aC13[3];
  int aN0[3], aN1[3], aN13[3];
  bf16x8 aAX0[3], aAX1[3], aAY0[3], aAY1[3];

  CALCADDR(0, aC0, aC1, aC13);
  LOADA(0, aC0, aC1, aC13, aAX0, aAX1);
  LOADA(1, aC0, aC1, aC13, aAY0, aAY1);

  for (int t3 = 0; t3 < 9; t3 += 3){
    TAPBODY(t3+0, bB0, bB1, bB2);
    TAPBODY(t3+1, bB1, bB2, bB0);
    TAPBODY(t3+2, bB2, bB0, bB1);
  }
#undef CALCADDR
#undef LOADB
#undef LOADA
#undef DOMFMA
#undef TAPBODY

  __syncthreads();   // all image-LDS reads done; smem reusable

  // zero xnL rows 82..95 for both images
  if (tid < 224){
    int im = tid / 112, r2 = tid % 112;
    int rr = 82 + (r2 >> 3), c = r2 & 7;
    *(i32x4*)(smem + im*12288 + rr*128 + ((c*16) ^ ((rr&7)<<4))) = (i32x4){0,0,0,0};
  }

  float t2c[4], lg[4], lb[4];
  #pragma unroll
  for (int j=0;j<4;j++){
    int col = j*16 + lr;
    float s2 = g2[col]*rsqrtf(v2[col]+1e-5f);
    t2c[j] = (b2c[col]-m2[col])*s2 + be2[col];
    lg[j] = ln1_g[col]; lb[j] = ln1_b[col];
  }

  float st0[4]={0,0,0,0}, st1[4]={0,0,0,0};
  float sx0[4]={0,0,0,0}, sx1[4]={0,0,0,0};

  #pragma unroll
  for (int rt=0;rt<3;rt++){
    #pragma unroll
    for (int e=0;e<4;e++){
      int row = (wv*3+rt)*16 + lq*4 + e;
      if (row < 162){
        int im = (row >= 81);
        int pix = row - im*81;
        int tsp = spiral_t(pix);
        const float* pe = pos_emb + (1+tsp)*64;
        float y[4], m1 = 0.f, m2v = 0.f;
        #pragma unroll
        for (int j=0;j<4;j++){
          y[j] = fmaxf(acc[rt][j][e] + t2c[j], 0.f) + pe[j*16+lr];
          m1 += y[j]; m2v = fmaf(y[j], y[j], m2v);
        }
        #pragma unroll
        for (int off=1; off<16; off<<=1){
          m1  += __shfl_xor(m1,  off, 64);
          m2v += __shfl_xor(m2v, off, 64);
        }
        float mean = m1*(1.f/64.f);
        float var  = m2v*(1.f/64.f) - mean*mean;
        float rs = rsqrtf(var + 1e-5f);
        int trow = 1 + tsp;
        char* dl = smem + im*12288 + trow*128;
        int sz = (trow & 7) << 4;
        #pragma unroll
        for (int j=0;j<4;j++){
          float xnv = (y[j]-mean)*rs*lg[j] + lb[j];
          *(u16*)(dl + (((j*16+lr)*2) ^ sz)) = f2bf(xnv);
          if (im == 0){ st0[j] += y[j]; sx0[j] += xnv; }
          else        { st1[j] += y[j]; sx1[j] += xnv; }
        }
      }
    }
  }

  #pragma unroll
  for (int j=0;j<4;j++){
    st0[j] += __shfl_xor(st0[j],16,64); st0[j] += __shfl_xor(st0[j],32,64);
    st1[j] += __shfl_xor(st1[j],16,64); st1[j] += __shfl_xor(st1[j],32,64);
    sx0[j] += __shfl_xor(sx0[j],16,64); sx0[j] += __shfl_xor(sx0[j],32,64);
    sx1[j] += __shfl_xor(sx1[j],16,64); sx1[j] += __shfl_xor(sx1[j],32,64);
  }
  float* partT = (float*)(smem + PTo);    // [4 wv][2 img][64 d] (dead after LN1 combine)
  float* partX = (float*)(smem + PXo);
  float* xsumL = (float*)(smem + XSo);    // [2 img][64 d] -> later XZl
  float* tsumL = (float*)(smem + TSUML);  // [2 img][64 d]
  float* sqsL  = (float*)(smem + SQSL);   // [2 img][64 d]
  if (lq == 0){
    #pragma unroll
    for (int j=0;j<4;j++){
      partT[wv*128 +       j*16+lr] = st0[j];
      partT[wv*128 + 64  + j*16+lr] = st1[j];
      partX[wv*128 +       j*16+lr] = sx0[j];
      partX[wv*128 + 64  + j*16+lr] = sx1[j];
    }
  }
  __syncthreads();
  if (tid < 128){
    int im = tid >> 6, d = tid & 63;
    float tt = partT[im*64+d] + partT[128+im*64+d] + partT[256+im*64+d] + partT[384+im*64+d];
    float xx = partX[im*64+d] + partX[128+im*64+d] + partX[256+im*64+d] + partX[384+im*64+d];
    float clsv = cls_tok[d] + pos_emb[d];
    float c1v = clsv, c2v = clsv*clsv;
    #pragma unroll
    for (int off=1; off<64; off<<=1){ c1v += __shfl_xor(c1v, off, 64); c2v += __shfl_xor(c2v, off, 64); }
    float cm = c1v*(1.f/64.f), cv = c2v*(1.f/64.f) - cm*cm;
    float cxn = (clsv - cm)*rsqrtf(cv + 1e-5f)*ln1_g[d] + ln1_b[d];
    *(u16*)(smem + im*12288 + d*2) = f2bf(cxn);     // xnL row 0 (swizzle term 0)
    tsumL[im*64 + d] = tt + clsv;
    xsumL[im*64 + d] = (xx + cxn) * (1.f/82.f);
  }
  __syncthreads();
  {
    int im = tid >> 7, d2 = tid & 127;
    int d = d2 >> 1, half = d2 & 1;
    float a = 0.f;
    int k0 = half*32;
    #pragma unroll
    for (int k=0;k<32;k++) a = fmaf(xsumL[im*64 + k0+k], Wst[(k0+k)*64+d], a);
    a += __shfl_xor(a, 1, 64);
    if (half == 0){
      a += bst[d];
      a = fmaxf(a, 0.f);
      a = 1.f/(1.f + __expf(-a));
      sqsL[im*64 + d] = a + bias_st[d];
    }
  }
  __syncthreads();   // xnL / tsumL / sqsL complete; xsumL consumed -> becomes XZl

  // ---- fused token mixer ----
  // B-frags (im-invariant): cc = wv*16+lr for each of Wb/Wc/Wd
  bf16x8 bfr[3][2];
  {
    int cc = wv*16 + lr;
    const float* Ws[3] = {Wb, Wc, Wd};
    #pragma unroll
    for (int w=0;w<3;w++)
      #pragma unroll
      for (int kk=0;kk<2;kk++){
        int k0 = kk*32 + lq*8;
        bf16x8 f;
        #pragma unroll
        for (int e=0;e<8;e++) f[e] = (short)f2bf(Ws[w][(k0+e)*64 + cc]);
        bfr[w][kk] = f;
      }
  }
  u16* AxL = (u16*)(smem + AXo);
  u16* BxL = (u16*)(smem + BXo);
  u16* CxL = (u16*)(smem + CXo);
  float* RCl = (float*)(smem + PTo);   // [2 im][4 seg][64]  (partT dead)
  float* PQl = (float*)(smem + PXo);   // [4 seg][2][64]     (partX dead, per-im reuse)
  float* XZl = (float*)(smem + XSo);   // [2 im][64]         (xsumL dead after squeeze)

  for (int im = 0; im < 2; im++){
    const char* xb = smem + im*12288;
    f32x4 facc[6][3];
    #pragma unroll
    for (int i=0;i<6;i++)
      #pragma unroll
      for (int w=0;w<3;w++) facc[i][w] = (f32x4){0.f,0.f,0.f,0.f};

    #pragma unroll
    for (int rt=0;rt<6;rt++){
      int row = rt*16 + lr;
      bf16x8 afr[2];
      #pragma unroll
      for (int kk=0;kk<2;kk++)
        afr[kk] = *(const bf16x8*)(xb + row*128 + ((kk*64 + lq*16) ^ ((row&7)<<4)));
      #pragma unroll
      for (int kk=0;kk<2;kk++)
        #pragma unroll
        for (int w=0;w<3;w++)
          facc[rt][w] = __builtin_amdgcn_mfma_f32_16x16x32_bf16(afr[kk], bfr[w][kk], facc[rt][w], 0, 0, 0);
    }

    {
      int d = wv*16 + lr;
      float bB = bbv[d], bC = bcv[d], bD = bdv[d];
      float xz = 0.f;
      #pragma unroll
      for (int rt=0;rt<6;rt++){
        #pragma unroll
        for (int e=0;e<4;e++){
          int t = rt*16 + lq*4 + e;
          if (t < 82){
            float B0 = facc[rt][0][e] + bB;
            float Cv = facc[rt][1][e] + bC;
            float Dr = facc[rt][2][e] + bD + delta_p[t*64+d];
            float D  = 1.f/(1.f + __expf(-Dr));
            float xv = bf2f(*(const u16*)(xb + t*128 + ((d*2) ^ ((t&7)<<4))));
            float z  = 1.f/(1.f + __expf(-xv));
            AxL[t*66+d] = f2bf(D * A_p[t*64+d]);
            BxL[t*66+d] = f2bf(D * B0 * xv);
            CxL[t*66+d] = f2bf(Cv * z);          // z folded into C
            xz = fmaf(xv, z, xz);                // scan-independent term
          }
        }
      }
      // reduce xz over lq (lanes ln^16, ln^32 share d)
      xz += __shfl_xor(xz, 16, 64);
      xz += __shfl_xor(xz, 32, 64);
      if (lq == 0) XZl[im*64 + d] = xz;
    }
    __syncthreads();

    // pass A: per-segment affine composition (P, Q) -- wave wv owns
    // timesteps [21*wv, 21*wv+21) (last segment 19)
    {
      int d = ln;
      int S = wv*21, E = (wv==3) ? 82 : S+21;
      float P = 1.f, Q = 0.f;
      for (int t = S; t < E; t++){
        float a  = bf2f(AxL[t*66+d]);
        float bx = bf2f(BxL[t*66+d]);
        Q = fmaf(a, Q, bx);
        P *= a;
      }
      PQl[(wv*2+0)*64 + d] = P;
      PQl[(wv*2+1)*64 + d] = Q;
    }
    __syncthreads();
    // prefix-compose s_start, then pass B: sequential replay, racc = sum(cz*s)
    {
      int d = ln;
      int S = wv*21, E = (wv==3) ? 82 : S+21;
      float s = 0.f;
      #pragma unroll
      for (int w2 = 0; w2 < 3; w2++)
        if (w2 < wv)
          s = fmaf(PQl[(w2*2+0)*64 + d], s, PQl[(w2*2+1)*64 + d]);
      float racc = 0.f;
      for (int t = S; t < E; t++){
        float a  = bf2f(AxL[t*66+d]);
        float bx = bf2f(BxL[t*66+d]);
        float cz = bf2f(CxL[t*66+d]);
        s = fmaf(a, s, bx);
        racc = fmaf(cz, s, racc);
      }
      RCl[im*256 + wv*64 + d] = racc;
    }
    __syncthreads();   // RC done; AxL/BxL/CxL free for next image
  }

  // final: pooled + LN2 + MLP for both images in parallel (waves 0 and 1)
  if (tid < 128){
    int im = wv, d = ln;
    float racc = RCl[im*256 + d] + RCl[im*256 + 64 + d]
               + RCl[im*256 + 128 + d] + RCl[im*256 + 192 + d]
               + sqsL[im*64 + d] * XZl[im*64 + d];
    float pooled = (tsumL[im*64 + d] + racc) * (1.f/82.f);
    float s1 = pooled, s2v = pooled*pooled;
    #pragma unroll
    for (int off=32; off>0; off>>=1){ s1 += __shfl_xor(s1, off, 64); s2v += __shfl_xor(s2v, off, 64); }
    float mean = s1*(1.f/64.f), var = s2v*(1.f/64.f) - mean*mean;
    float yn = (pooled - mean)*rsqrtf(var + 1e-5f)*ln2_g[d] + ln2_b[d];
    float a1 = bm1[d];
    for (int k=0;k<64;k++) a1 = fmaf(__shfl(yn, k, 64), Wm1[k*64+d], a1);
    float hg = 0.5f*a1*(1.f + erff(a1*0.70710678118654752f));
    float a2 = bm2[d];
    for (int k=0;k<64;k++) a2 = fmaf(__shfl(hg, k, 64), Wm2[k*64+d], a2);
    out[(size_t)(img0+im)*64 + d] = pooled + a2;
  }
}

extern "C" void kernel_launch(void* const* d_in, const int* in_sizes, int n_in,
                              void* d_out, int out_size, void* d_ws, size_t ws_size,
                              hipStream_t stream){
  const float* x       = (const float*)d_in[0];
  const float* w3      = (const float*)d_in[1];
  const float* b3      = (const float*)d_in[2];
  const float* g3      = (const float*)d_in[3];
  const float* be3     = (const float*)d_in[4];
  const float* m3      = (const float*)d_in[5];
  const float* v3      = (const float*)d_in[6];
  const float* w2c     = (const float*)d_in[7];
  const float* b2c     = (const float*)d_in[8];
  const float* g2      = (const float*)d_in[9];
  const float* be2     = (const float*)d_in[10];
  const float* m2      = (const float*)d_in[11];
  const float* v2      = (const float*)d_in[12];
  const float* pos_emb = (const float*)d_in[13];
  const float* cls_tok = (const float*)d_in[14];
  const float* ln1_g   = (const float*)d_in[15];
  const float* ln1_b   = (const float*)d_in[16];
  const float* Wb      = (const float*)d_in[17];
  const float* bbv     = (const float*)d_in[18];
  const float* Wc      = (const float*)d_in[19];
  const float* bc      = (const float*)d_in[20];
  const float* Wd      = (const float*)d_in[21];
  const float* bd      = (const float*)d_in[22];
  const float* delta_p = (const float*)d_in[23];
  const float* A_p     = (const float*)d_in[24];
  const float* Wst     = (const float*)d_in[25];
  const float* bst     = (const float*)d_in[26];
  const float* bias_st = (const float*)d_in[27];
  const float* ln2_g   = (const float*)d_in[28];
  const float* ln2_b   = (const float*)d_in[29];
  const float* Wm1     = (const float*)d_in[30];
  const float* bm1     = (const float*)d_in[31];
  const float* Wm2     = (const float*)d_in[32];
  const float* bm2     = (const float*)d_in[33];

  // workspace layout (bytes), peak = 159,547,392:
  //   h1   [0,          159252480)  (conv3d -> conv2d)
  //   Wt2  [159252480,  159547392)  (conv3d wt-blocks -> conv2d)
  char* ws = (char*)d_ws;
  u16*   h1   = (u16*)ws;
  u16*   Wt2  = (u16*)(ws + 159252480);

  k_conv3d<<<4672, 256, 0, stream>>>(x, w3, b3, g3, be3, m3, v3,
                                     w2c, g2, v2, h1, Wt2);
  k_conv2d<<<2048, 256, 0, stream>>>(h1, Wt2, b2c, g2, be2, m2, v2,
                                     pos_emb, cls_tok, ln1_g, ln1_b,
                                     Wst, bst, bias_st,
                                     Wb, Wc, Wd, bbv, bc, bd, delta_p, A_p,
                                     ln2_g, ln2_b, Wm1, bm1, Wm2, bm2,
                                     (float*)d_out);
}